// Round 1
// baseline (491.038 us; speedup 1.0000x reference)
//
#include <hip/hip_runtime.h>
#include <hip/hip_cooperative_groups.h>
#include <math.h>

namespace cg = cooperative_groups;

typedef _Float16 f16;
typedef _Float16 f16x8 __attribute__((ext_vector_type(8)));
typedef _Float16 f16x4 __attribute__((ext_vector_type(4)));
typedef float f32x4 __attribute__((ext_vector_type(4)));

#define NROWS 12288
#define NFEAT 4096
#define DDIM  256
#define KDIM  1000
#define KPAD  1024
#define NSLAB 8

// workspace layout (bytes)
static const size_t OFF_A16 = 0;           // 12288*256 f16 = 6,291,456
static const size_t OFF_BF  = 6291456;     // 1024*256 f16  =   524,288
static const size_t OFF_E16 = 6815744;     // 12288*1024 f16= 25,165,824
static const size_t OFF_SL  = 31981568;    // 3 * 8 * 1024 f32 slabs

__device__ inline float wsum(float v) {
#pragma unroll
    for (int m = 32; m >= 1; m >>= 1) v += __shfl_xor(v, m, 64);
    return v;
}

// ===========================================================================
// Fused phase bodies (byte-identical math to the 5-kernel path)
// ===========================================================================

__device__ __forceinline__ void gemm_phase(int b, const f16* __restrict__ A16,
                                           const f16* __restrict__ Bf,
                                           f16* __restrict__ E16,
                                           float* __restrict__ S0sl, char* smem) {
    f16 (*Es)[136] = (f16(*)[136])smem;
    int tid = threadIdx.x;
    int wave = tid >> 6, lane = tid & 63;
    int lm = lane & 15, q = lane >> 4;
    int by = b >> 3, bx = b & 7;
    int row0 = by * 128, col0 = bx * 128;
    int wm = (wave >> 1) * 64, wn = (wave & 1) * 64;
    const f16* Ab = A16 + (size_t)(row0 + wm + lm) * DDIM + q * 8;
    const f16* Bb = Bf  + (size_t)(col0 + wn + lm) * DDIM + q * 8;

    f32x4 acc[4][4];
#pragma unroll
    for (int i = 0; i < 4; ++i)
#pragma unroll
        for (int j = 0; j < 4; ++j) acc[i][j] = (f32x4){0.f, 0.f, 0.f, 0.f};

#pragma unroll
    for (int kt = 0; kt < DDIM; kt += 32) {
        f16x8 a[4], bfr[4];
#pragma unroll
        for (int ms = 0; ms < 4; ++ms) a[ms] = *(const f16x8*)(Ab + (size_t)ms * 16 * DDIM + kt);
#pragma unroll
        for (int ns = 0; ns < 4; ++ns) bfr[ns] = *(const f16x8*)(Bb + (size_t)ns * 16 * DDIM + kt);
#pragma unroll
        for (int ms = 0; ms < 4; ++ms)
#pragma unroll
            for (int ns = 0; ns < 4; ++ns)
                acc[ms][ns] = __builtin_amdgcn_mfma_f32_16x16x32_f16(a[ms], bfr[ns], acc[ms][ns], 0, 0, 0);
    }

    float colp[4] = {0.f, 0.f, 0.f, 0.f};
#pragma unroll
    for (int ms = 0; ms < 4; ++ms) {
#pragma unroll
        for (int ns = 0; ns < 4; ++ns) {
            int gc = col0 + wn + ns * 16 + lm;
            bool ok = gc < KDIM;
#pragma unroll
            for (int r = 0; r < 4; ++r) {
                float e = ok ? __expf(acc[ms][ns][r] * 20.0f) : 0.0f;
                colp[ns] += e;
                Es[wm + ms * 16 + q * 4 + r][wn + ns * 16 + lm] = (f16)e;
            }
        }
    }
#pragma unroll
    for (int ns = 0; ns < 4; ++ns) {
        colp[ns] += __shfl_xor(colp[ns], 16, 64);
        colp[ns] += __shfl_xor(colp[ns], 32, 64);
    }
    __syncthreads();
    {
        int r = tid >> 1, half = tid & 1;
        const f16* src = &Es[r][half * 64];
        f16* dst = E16 + (size_t)(row0 + r) * KPAD + col0 + half * 64;
#pragma unroll
        for (int i = 0; i < 8; ++i)
            *(uint4*)(dst + i * 8) = *(const uint4*)(src + i * 8);
    }
    __syncthreads();
    float* cred = (float*)smem;
    if (tid < 128) cred[tid] = 0.f;
    __syncthreads();
    if (lane < 16) {
#pragma unroll
        for (int ns = 0; ns < 4; ++ns)
            atomicAdd(&cred[wn + ns * 16 + lane], colp[ns]);   // LDS atomic
    }
    __syncthreads();
    if (tid < 128)
        atomicAdd(&S0sl[(size_t)(by & 7) * KPAD + col0 + tid], cred[tid]);
}

__device__ __forceinline__ void rowpass_phase(int bid, const f16* __restrict__ E16,
                                              const float* __restrict__ SinSl,
                                              float* __restrict__ SoutSl, char* smem) {
    float* rl = (float*)smem;                       // KPAD f32 = 4 KB
    float (*cols4)[KPAD] = (float(*)[KPAD])(smem + 4096);  // 16 KB
    int tid = threadIdx.x;
    {
        int n = tid * 4;
        float4 s = *(const float4*)(SinSl + n);
#pragma unroll
        for (int j = 1; j < NSLAB; ++j) {
            float4 t = *(const float4*)(SinSl + (size_t)j * KPAD + n);
            s.x += t.x; s.y += t.y; s.z += t.z; s.w += t.w;
        }
        float4 o;
        o.x = (n + 0 < KDIM) ? 1.0f / (1000.0f * s.x) : 0.0f;
        o.y = (n + 1 < KDIM) ? 1.0f / (1000.0f * s.y) : 0.0f;
        o.z = (n + 2 < KDIM) ? 1.0f / (1000.0f * s.z) : 0.0f;
        o.w = (n + 3 < KDIM) ? 1.0f / (1000.0f * s.w) : 0.0f;
        *(float4*)(rl + n) = o;
    }
    __syncthreads();
    int wave = tid >> 6, lane = tid & 63;
    int n0 = lane * 16;
    float rv[16];
#pragma unroll
    for (int i = 0; i < 16; ++i) rv[i] = rl[n0 + i];

    int rowbase = bid * 16 + wave * 4;
    const f16* erb = E16 + (size_t)rowbase * KPAD + n0;
    f16x8 e[4][2];
#pragma unroll
    for (int j = 0; j < 4; ++j) {
        e[j][0] = *(const f16x8*)(erb + (size_t)j * KPAD);
        e[j][1] = *(const f16x8*)(erb + (size_t)j * KPAD + 8);
    }
    float p[4];
#pragma unroll
    for (int j = 0; j < 4; ++j) {
        float acc = 0.f;
#pragma unroll
        for (int i = 0; i < 8; ++i) {
            acc += (float)e[j][0][i] * rv[i];
            acc += (float)e[j][1][i] * rv[8 + i];
        }
        p[j] = acc;
    }
#pragma unroll
    for (int m = 32; m >= 1; m >>= 1) {
        float t0 = __shfl_xor(p[0], m, 64);
        float t1 = __shfl_xor(p[1], m, 64);
        float t2 = __shfl_xor(p[2], m, 64);
        float t3 = __shfl_xor(p[3], m, 64);
        p[0] += t0; p[1] += t1; p[2] += t2; p[3] += t3;
    }
    float c[4];
#pragma unroll
    for (int j = 0; j < 4; ++j) c[j] = 1.0f / (12288.0f * p[j]);
    float ca[16];
#pragma unroll
    for (int i = 0; i < 16; ++i) {
        int h = i >> 3, ii = i & 7;
        ca[i] = (float)e[0][h][ii] * c[0] + (float)e[1][h][ii] * c[1]
              + (float)e[2][h][ii] * c[2] + (float)e[3][h][ii] * c[3];
    }
#pragma unroll
    for (int i = 0; i < 16; ++i) {
        int idx = (i + lane) & 15;
        cols4[wave][n0 + idx] = ca[idx];
    }
    __syncthreads();
    float* outSlab = SoutSl + (size_t)(bid & 7) * KPAD;
    for (int n = tid; n < KPAD; n += 256)
        atomicAdd(&outSlab[n],
                  cols4[0][n] + cols4[1][n] + cols4[2][n] + cols4[3][n]);
}

__device__ __forceinline__ void out_phase(int b, const f16* __restrict__ E16,
                                          const float* __restrict__ S2sl,
                                          float* __restrict__ out, char* smem) {
    float* rl = (float*)smem;
    int tid = threadIdx.x;
    {
        int n = tid * 4;
        float4 s = *(const float4*)(S2sl + n);
#pragma unroll
        for (int j = 1; j < NSLAB; ++j) {
            float4 t = *(const float4*)(S2sl + (size_t)j * KPAD + n);
            s.x += t.x; s.y += t.y; s.z += t.z; s.w += t.w;
        }
        float4 o;
        o.x = (n + 0 < KDIM) ? 1.0f / (1000.0f * s.x) : 0.0f;
        o.y = (n + 1 < KDIM) ? 1.0f / (1000.0f * s.y) : 0.0f;
        o.z = (n + 2 < KDIM) ? 1.0f / (1000.0f * s.z) : 0.0f;
        o.w = (n + 3 < KDIM) ? 1.0f / (1000.0f * s.w) : 0.0f;
        *(float4*)(rl + n) = o;
    }
    __syncthreads();
    int wave = tid >> 6, lane = tid & 63;
    int n0 = lane * 16;
    float rv[16];
#pragma unroll
    for (int i = 0; i < 16; ++i) rv[i] = rl[n0 + i];
    // 768 blocks x 4 waves = 3072 wave-slots cover 4096 rows in <=2 trips
    for (int row = b * 4 + wave; row < NFEAT; row += 3072) {
        const f16* er = E16 + (size_t)row * KPAD + n0;
        f16x8 e0 = *(const f16x8*)er;
        f16x8 e1 = *(const f16x8*)(er + 8);
        float w[16];
        float p = 0.f;
#pragma unroll
        for (int i = 0; i < 8; ++i) {
            w[i] = (float)e0[i] * rv[i];
            w[8 + i] = (float)e1[i] * rv[8 + i];
        }
#pragma unroll
        for (int i = 0; i < 16; ++i) p += w[i];
        p = wsum(p);
        float inv = 1.0f / p;
        float* orow = out + (size_t)row * KDIM;
#pragma unroll
        for (int i = 0; i < 16; i += 4) {
            int n = n0 + i;
            if (n + 3 < KDIM) {
                float4 o = { w[i] * inv, w[i + 1] * inv, w[i + 2] * inv, w[i + 3] * inv };
                *(float4*)(orow + n) = o;
            } else {
#pragma unroll
                for (int t = 0; t < 4; ++t)
                    if (n + t < KDIM) orow[n + t] = w[i + t] * inv;
            }
        }
    }
}

// ===========================================================================
// Single cooperative kernel: prep -> gemm+exp+colsum -> row/col pass x2 -> out
// 768 blocks = 3 blocks/CU co-resident (LDS 34816*3 = 102KB, VGPR capped 168).
// 4 grid.sync()s replace 4 kernel-boundary drains.
// ===========================================================================
__global__ __launch_bounds__(256, 3)
void fused_k(const float* __restrict__ feats, const float* __restrict__ queue,
             const float* __restrict__ head, f16* __restrict__ A16,
             f16* __restrict__ Bf, f16* __restrict__ E16,
             float* __restrict__ slabs, float* __restrict__ out) {
    cg::grid_group grid = cg::this_grid();
    __shared__ __align__(16) char smem[34816];
    int b = blockIdx.x, tid = threadIdx.x;
    int wave = tid >> 6, lane = tid & 63;

    float* S0sl = slabs;
    float* S1sl = slabs + NSLAB * KPAD;
    float* S2sl = slabs + 2 * NSLAB * KPAD;

    // ---- phase P: normalize A rows (16/block), head transpose (b<32), zero slabs
#pragma unroll
    for (int j = 0; j < 4; ++j) {
        int row = b * 16 + wave * 4 + j;
        const float* src = (row < NFEAT) ? feats + (size_t)row * DDIM
                                         : queue + (size_t)(row - NFEAT) * DDIM;
        float4 v = *(const float4*)(src + lane * 4);
        float s = wsum(v.x * v.x + v.y * v.y + v.z * v.z + v.w * v.w);
        float inv = 1.0f / sqrtf(fmaxf(s, 1e-24f));
        f16x4 o = { (f16)(v.x * inv), (f16)(v.y * inv), (f16)(v.z * inv), (f16)(v.w * inv) };
        *(f16x4*)(A16 + (size_t)row * DDIM + lane * 4) = o;
    }
    if (b < 32) {
        float* rin = (float*)smem;
        int kb = b * 8;
        for (int j = 0; j < 2; ++j) {
            int k = kb + wave * 2 + j;
            const float* hr = head + (size_t)k * KDIM;
            float s = 0.f;
            for (int n = lane; n < KDIM; n += 64) { float v = hr[n]; s += v * v; }
            s = wsum(s);
            if (lane == 0) rin[wave * 2 + j] = 1.0f / sqrtf(fmaxf(s, 1e-24f));
        }
        __syncthreads();
        float r[8];
#pragma unroll
        for (int i = 0; i < 8; ++i) r[i] = rin[i];
        for (int n = tid; n < KDIM; n += 256) {
            f16 tmp[8];
#pragma unroll
            for (int i = 0; i < 8; ++i)
                tmp[i] = (f16)(head[(size_t)(kb + i) * KDIM + n] * r[i]);
            *(uint4*)(Bf + (size_t)n * DDIM + kb) = *(const uint4*)(tmp);
        }
    } else if (b < 56) {
        float* dst = slabs + (size_t)(b - 32) * KPAD + tid * 4;   // 24 blocks x 1024 f32 = all 3 slab sets
        *(float4*)dst = make_float4(0.f, 0.f, 0.f, 0.f);
    }

    grid.sync();
    gemm_phase(b, A16, Bf, E16, S0sl, smem);
    grid.sync();
    rowpass_phase(b, E16, S0sl, S1sl, smem);
    grid.sync();
    rowpass_phase(b, E16, S1sl, S2sl, smem);
    grid.sync();
    out_phase(b, E16, S2sl, out, smem);
}

// ===========================================================================
// Fallback path: the previous 5-kernel pipeline (unchanged), used only if the
// cooperative launch is rejected.
// ===========================================================================
__global__ __launch_bounds__(256)
void prep_k(const float* __restrict__ feats, const float* __restrict__ queue,
            const float* __restrict__ head, f16* __restrict__ A16,
            f16* __restrict__ Bf, float* __restrict__ slabs) {
    int b = blockIdx.x, tid = threadIdx.x;
    int wave = tid >> 6, lane = tid & 63;
    if (b < 3072) {
        int row = b * 4 + wave;
        const float* src = (row < NFEAT) ? feats + (size_t)row * DDIM
                                         : queue + (size_t)(row - NFEAT) * DDIM;
        float4 v = *(const float4*)(src + lane * 4);
        float s = wsum(v.x * v.x + v.y * v.y + v.z * v.z + v.w * v.w);
        float inv = 1.0f / sqrtf(fmaxf(s, 1e-24f));
        f16x4 o = { (f16)(v.x * inv), (f16)(v.y * inv), (f16)(v.z * inv), (f16)(v.w * inv) };
        *(f16x4*)(A16 + (size_t)row * DDIM + lane * 4) = o;
    } else if (b < 3104) {
        __shared__ float rin[8];
        int kb = (b - 3072) * 8;
        for (int j = 0; j < 2; ++j) {
            int k = kb + wave * 2 + j;
            const float* hr = head + (size_t)k * KDIM;
            float s = 0.f;
            for (int n = lane; n < KDIM; n += 64) { float v = hr[n]; s += v * v; }
            s = wsum(s);
            if (lane == 0) rin[wave * 2 + j] = 1.0f / sqrtf(fmaxf(s, 1e-24f));
        }
        __syncthreads();
        float r[8];
#pragma unroll
        for (int i = 0; i < 8; ++i) r[i] = rin[i];
        for (int n = tid; n < KDIM; n += 256) {
            f16 tmp[8];
#pragma unroll
            for (int i = 0; i < 8; ++i)
                tmp[i] = (f16)(head[(size_t)(kb + i) * KDIM + n] * r[i]);
            *(uint4*)(Bf + (size_t)n * DDIM + kb) = *(const uint4*)(tmp);
        }
    } else {
        float* dst = slabs + (size_t)(b - 3104) * KPAD + tid * 4;
        *(float4*)dst = make_float4(0.f, 0.f, 0.f, 0.f);
    }
}

__global__ __launch_bounds__(256, 3)
void gemm_exp_k(const f16* __restrict__ A16, const f16* __restrict__ Bf,
                f16* __restrict__ E16, float* __restrict__ S0sl) {
    __shared__ __align__(16) char smem[34816];
    int b = (int)(blockIdx.y * 8 + blockIdx.x);
    // re-map to the fused helper's b: by = b/8? fused uses by=b>>3, bx=b&7
    gemm_phase((int)((blockIdx.y << 3) | blockIdx.x), A16, Bf, E16, S0sl, smem);
    (void)b;
}

__global__ __launch_bounds__(256)
void rowpass_k(const f16* __restrict__ E16, const float* __restrict__ SinSl,
               float* __restrict__ SoutSl) {
    __shared__ __align__(16) char smem[20480];
    rowpass_phase(blockIdx.x, E16, SinSl, SoutSl, smem);
}

__global__ __launch_bounds__(256)
void out_k(const f16* __restrict__ E16, const float* __restrict__ S2sl,
           float* __restrict__ out) {
    __shared__ __align__(16) char smem[4096];
    float* rl = (float*)smem;
    int tid = threadIdx.x;
    {
        int n = tid * 4;
        float4 s = *(const float4*)(S2sl + n);
#pragma unroll
        for (int j = 1; j < NSLAB; ++j) {
            float4 t = *(const float4*)(S2sl + (size_t)j * KPAD + n);
            s.x += t.x; s.y += t.y; s.z += t.z; s.w += t.w;
        }
        float4 o;
        o.x = (n + 0 < KDIM) ? 1.0f / (1000.0f * s.x) : 0.0f;
        o.y = (n + 1 < KDIM) ? 1.0f / (1000.0f * s.y) : 0.0f;
        o.z = (n + 2 < KDIM) ? 1.0f / (1000.0f * s.z) : 0.0f;
        o.w = (n + 3 < KDIM) ? 1.0f / (1000.0f * s.w) : 0.0f;
        *(float4*)(rl + n) = o;
    }
    __syncthreads();
    int wave = tid >> 6, lane = tid & 63;
    int n0 = lane * 16;
    float rv[16];
#pragma unroll
    for (int i = 0; i < 16; ++i) rv[i] = rl[n0 + i];
    int row = blockIdx.x * 4 + wave;
    const f16* er = E16 + (size_t)row * KPAD + n0;
    f16x8 e0 = *(const f16x8*)er;
    f16x8 e1 = *(const f16x8*)(er + 8);
    float w[16];
    float p = 0.f;
#pragma unroll
    for (int i = 0; i < 8; ++i) {
        w[i] = (float)e0[i] * rv[i];
        w[8 + i] = (float)e1[i] * rv[8 + i];
    }
#pragma unroll
    for (int i = 0; i < 16; ++i) p += w[i];
    p = wsum(p);
    float inv = 1.0f / p;
    float* orow = out + (size_t)row * KDIM;
#pragma unroll
    for (int i = 0; i < 16; i += 4) {
        int n = n0 + i;
        if (n + 3 < KDIM) {
            float4 o = { w[i] * inv, w[i + 1] * inv, w[i + 2] * inv, w[i + 3] * inv };
            *(float4*)(orow + n) = o;
        } else {
#pragma unroll
            for (int t = 0; t < 4; ++t)
                if (n + t < KDIM) orow[n + t] = w[i + t] * inv;
        }
    }
}

// ---------------------------------------------------------------------------
extern "C" void kernel_launch(void* const* d_in, const int* in_sizes, int n_in,
                              void* d_out, int out_size, void* d_ws, size_t ws_size,
                              hipStream_t stream) {
    (void)in_sizes; (void)n_in; (void)out_size; (void)ws_size;
    const float* feats = (const float*)d_in[0];   // [4096,256]
    const float* head  = (const float*)d_in[1];   // [256,1000]
    const float* queue = (const float*)d_in[2];   // [8192,256]
    float* out = (float*)d_out;                   // [4096,1000]

    char* ws = (char*)d_ws;
    f16*   A16   = (f16*)(ws + OFF_A16);
    f16*   Bf    = (f16*)(ws + OFF_BF);
    f16*   E16   = (f16*)(ws + OFF_E16);
    float* slabs = (float*)(ws + OFF_SL);
    float* S0sl  = slabs;
    float* S1sl  = slabs + NSLAB * KPAD;
    float* S2sl  = slabs + 2 * NSLAB * KPAD;

    void* args[] = { (void*)&feats, (void*)&queue, (void*)&head, (void*)&A16,
                     (void*)&Bf, (void*)&E16, (void*)&slabs, (void*)&out };
    hipError_t err = hipLaunchCooperativeKernel((const void*)fused_k, dim3(768),
                                                dim3(256), (void**)args, 0, stream);
    if (err != hipSuccess) {
        // fallback: previous 5-kernel pipeline
        prep_k<<<3128, 256, 0, stream>>>(feats, queue, head, A16, Bf, slabs);
        gemm_exp_k<<<dim3(8, 96), 256, 0, stream>>>(A16, Bf, E16, S0sl);
        rowpass_k<<<768, 256, 0, stream>>>(E16, S0sl, S1sl);
        rowpass_k<<<768, 256, 0, stream>>>(E16, S1sl, S2sl);
        out_k<<<NFEAT / 4, 256, 0, stream>>>(E16, S2sl, out);
    }
}

// Round 2
// 287.231 us; speedup vs baseline: 1.7096x; 1.7096x over previous
//
#include <hip/hip_runtime.h>
#include <math.h>

typedef _Float16 f16;
typedef _Float16 f16x8 __attribute__((ext_vector_type(8)));
typedef _Float16 f16x4 __attribute__((ext_vector_type(4)));
typedef float f32x4 __attribute__((ext_vector_type(4)));

#define NROWS 12288
#define NFEAT 4096
#define DDIM  256
#define KDIM  1000
#define KPAD  1024
#define NSLAB 8
#define NBLK  768

// ---------------- fused workspace layout (bytes) ----------------
static const size_t F_RN  = 0;        // 256 f32 head-row inverse norms
static const size_t F_S0  = 1024;     // 1024 f32 colsum slabs
static const size_t F_S1  = 5120;
static const size_t F_S2  = 9216;
static const size_t F_R1  = 13312;    // 12288 f32 rowsum slabs
static const size_t F_R2  = 62464;
static const size_t F_R3  = 111616;
static const size_t F_BAR = 160768;   // int[8*32 + 32]: 8 padded sub + master
static const size_t F_ZERO = 163840;  // memset length

// ---------------- fallback (5-kernel) workspace layout ----------------
static const size_t OFF_A16 = 0;
static const size_t OFF_BF  = 6291456;
static const size_t OFF_E16 = 6815744;
static const size_t OFF_SL  = 31981568;

// ---------------- LDS layout for fused kernel (bytes) ----------------
// E tile [128][128] f16, XOR-swizzled                    0 .. 32768
// union: gemm panels  A[128][32] f16 swz  32768..40960
//                     B[128][32] f16 swz  40960..49152
//        r-phase:     Ul 128 f32          32768..33280
//                     Vl 128 f32          33280..33792
//                     CA 128 f32 (+pad)   33792..35840
// rinvA 128 f32                           49152..49664
// rinvB 256 f32                           49664..50688
#define S_E    0
#define S_PANA 32768
#define S_PANB 40960
#define S_UL   32768
#define S_VL   33280
#define S_CA   33792
#define S_RINVA 49152
#define S_RINVB 49664
#define S_TOTAL 50688

__device__ inline float wsum(float v) {
#pragma unroll
    for (int m = 32; m >= 1; m >>= 1) v += __shfl_xor(v, m, 64);
    return v;
}

// E-tile byte address with bank swizzle (keeps 16B alignment: XOR of bits 4..6)
__device__ __forceinline__ int esw(int row, int bytecol) {
    return (row * 256 + bytecol) ^ ((row & 7) << 4);
}
// panel byte address (row stride 64 B) with swizzle
__device__ __forceinline__ int psw(int row, int bytecol) {
    return (row * 64 + bytecol) ^ ((row & 7) << 4);
}

// hierarchical no-flush grid barrier: monotonic counters, 8 sub + 1 master.
// All cross-block data goes through device-scope atomics, so no L2
// writeback/invalidate is needed (this is the whole point vs grid.sync()).
__device__ __forceinline__ void gridbar(int* bar, int phase) {
    __syncthreads();
    if (threadIdx.x == 0) {
        int* sub = bar + (blockIdx.x & 7) * 32;
        int* master = bar + 256;
        int v = __hip_atomic_fetch_add(sub, 1, __ATOMIC_ACQ_REL, __HIP_MEMORY_SCOPE_AGENT);
        if (v == phase * 96 + 95)
            __hip_atomic_fetch_add(master, 1, __ATOMIC_ACQ_REL, __HIP_MEMORY_SCOPE_AGENT);
        while (__hip_atomic_load(master, __ATOMIC_RELAXED, __HIP_MEMORY_SCOPE_AGENT) < phase * 8 + 8)
            __builtin_amdgcn_s_sleep(4);
        __builtin_amdgcn_fence(__ATOMIC_ACQUIRE, "agent");
    }
    __syncthreads();
}

// ===========================================================================
// Fully-fused persistent kernel. 768 blocks (3/CU), E-tile lives in LDS,
// 7 cheap barriers replace 4 kernel-boundary L2 flushes.
// ===========================================================================
__global__ __launch_bounds__(256, 3)
void fused2_k(const float* __restrict__ feats, const float* __restrict__ queue,
              const float* __restrict__ head, float* __restrict__ out,
              char* __restrict__ ws) {
    __shared__ __align__(16) char smem[S_TOTAL];
    float* rnG  = (float*)(ws + F_RN);
    float* S0g  = (float*)(ws + F_S0);
    float* S1g  = (float*)(ws + F_S1);
    float* S2g  = (float*)(ws + F_S2);
    float* R1g  = (float*)(ws + F_R1);
    float* R2g  = (float*)(ws + F_R2);
    float* R3g  = (float*)(ws + F_R3);
    int*   bar  = (int*)(ws + F_BAR);

    const int b = blockIdx.x, tid = threadIdx.x;
    const int wave = tid >> 6, lane = tid & 63;
    const int by = b >> 3, bx = b & 7;
    const int rowbase = by * 128, col0 = bx * 128;

    float* rinvA = (float*)(smem + S_RINVA);
    float* rinvB = (float*)(smem + S_RINVB);
    float* Ul = (float*)(smem + S_UL);
    float* Vl = (float*)(smem + S_VL);
    float* CA = (float*)(smem + S_CA);

    // ---------------- P0: head row norms (blocks 0..31) + A row norms ------
    if (b < 32) {
        float* rin = (float*)(smem + S_PANA);
        int kb = b * 8;
        for (int j = 0; j < 2; ++j) {
            int k = kb + wave * 2 + j;
            const float* hr = head + (size_t)k * KDIM;
            float s = 0.f;
            for (int n = lane; n < KDIM; n += 64) { float v = hr[n]; s += v * v; }
            s = wsum(s);
            if (lane == 0) rin[wave * 2 + j] = 1.0f / sqrtf(fmaxf(s, 1e-24f));
        }
        __syncthreads();
        if (tid < 8)
            __hip_atomic_store(&rnG[kb + tid], rin[tid], __ATOMIC_RELAXED,
                               __HIP_MEMORY_SCOPE_AGENT);
        __syncthreads();
    }
    for (int i = 0; i < 32; ++i) {
        int r = wave * 32 + i;
        int grow = rowbase + r;
        const float* src = (grow < NFEAT) ? feats + (size_t)grow * DDIM
                                          : queue + (size_t)(grow - NFEAT) * DDIM;
        float4 v = *(const float4*)(src + lane * 4);
        float s = wsum(v.x * v.x + v.y * v.y + v.z * v.z + v.w * v.w);
        if (lane == 0) rinvA[r] = 1.0f / sqrtf(fmaxf(s, 1e-24f));
    }
    gridbar(bar, 0);

    // ---------------- GEMM: panels from gmem -> LDS, MFMA, E -> LDS --------
    rinvB[tid] = __hip_atomic_load(&rnG[tid], __ATOMIC_RELAXED, __HIP_MEMORY_SCOPE_AGENT);
    if (tid + 256 < 256) {} // (256 threads cover 256 entries exactly)
    __syncthreads();

    const int lm = lane & 15, q = lane >> 4;
    const int wm = (wave >> 1) * 64, wn = (wave & 1) * 64;

    f32x4 acc[4][4];
#pragma unroll
    for (int i = 0; i < 4; ++i)
#pragma unroll
        for (int j = 0; j < 4; ++j) acc[i][j] = (f32x4){0.f, 0.f, 0.f, 0.f};

    for (int kt = 0; kt < DDIM; kt += 32) {
        // stage A panel: thread -> (row r, half h), 16 f32 -> 16 f16
        {
            int r = tid >> 1, h = tid & 1;
            int grow = rowbase + r;
            const float* src = ((grow < NFEAT) ? feats + (size_t)grow * DDIM
                                               : queue + (size_t)(grow - NFEAT) * DDIM)
                               + kt + h * 16;
            float4 v0 = *(const float4*)(src);
            float4 v1 = *(const float4*)(src + 4);
            float4 v2 = *(const float4*)(src + 8);
            float4 v3 = *(const float4*)(src + 12);
            float sc = rinvA[r];
            f16 tmp[16];
            tmp[0]=(f16)(v0.x*sc); tmp[1]=(f16)(v0.y*sc); tmp[2]=(f16)(v0.z*sc); tmp[3]=(f16)(v0.w*sc);
            tmp[4]=(f16)(v1.x*sc); tmp[5]=(f16)(v1.y*sc); tmp[6]=(f16)(v1.z*sc); tmp[7]=(f16)(v1.w*sc);
            tmp[8]=(f16)(v2.x*sc); tmp[9]=(f16)(v2.y*sc); tmp[10]=(f16)(v2.z*sc); tmp[11]=(f16)(v2.w*sc);
            tmp[12]=(f16)(v3.x*sc); tmp[13]=(f16)(v3.y*sc); tmp[14]=(f16)(v3.z*sc); tmp[15]=(f16)(v3.w*sc);
            *(uint4*)(smem + S_PANA + psw(r, h * 32))      = ((const uint4*)tmp)[0];
            *(uint4*)(smem + S_PANA + psw(r, h * 32 + 16)) = ((const uint4*)tmp)[1];
        }
        // stage B panel: thread -> (col c, half h): gather 16 k-values
        {
            int c = tid >> 1, h = tid & 1;
            int gc = col0 + c;
            f16 tb[16];
            if (gc < KDIM) {
#pragma unroll
                for (int j = 0; j < 16; ++j) {
                    int d = kt + h * 16 + j;
                    tb[j] = (f16)(head[(size_t)d * KDIM + gc] * rinvB[d]);
                }
            } else {
#pragma unroll
                for (int j = 0; j < 16; ++j) tb[j] = (f16)0.f;
            }
            *(uint4*)(smem + S_PANB + psw(c, h * 32))      = ((const uint4*)tb)[0];
            *(uint4*)(smem + S_PANB + psw(c, h * 32 + 16)) = ((const uint4*)tb)[1];
        }
        __syncthreads();
        f16x8 a[4], bb[4];
#pragma unroll
        for (int ms = 0; ms < 4; ++ms)
            a[ms] = *(const f16x8*)(smem + S_PANA + psw(wm + ms * 16 + lm, q * 16));
#pragma unroll
        for (int ns = 0; ns < 4; ++ns)
            bb[ns] = *(const f16x8*)(smem + S_PANB + psw(wn + ns * 16 + lm, q * 16));
#pragma unroll
        for (int ms = 0; ms < 4; ++ms)
#pragma unroll
            for (int ns = 0; ns < 4; ++ns)
                acc[ms][ns] = __builtin_amdgcn_mfma_f32_16x16x32_f16(a[ms], bb[ns], acc[ms][ns], 0, 0, 0);
        __syncthreads();
    }

    // exp + E->LDS (swizzled) + colsum partials
    float colp[4] = {0.f, 0.f, 0.f, 0.f};
#pragma unroll
    for (int ms = 0; ms < 4; ++ms) {
#pragma unroll
        for (int ns = 0; ns < 4; ++ns) {
            int gc = col0 + wn + ns * 16 + lm;
            bool ok = gc < KDIM;
            int col = wn + ns * 16 + lm;
#pragma unroll
            for (int rr = 0; rr < 4; ++rr) {
                float e = ok ? __expf(acc[ms][ns][rr] * 20.0f) : 0.0f;
                colp[ns] += e;
                int row = wm + ms * 16 + q * 4 + rr;
                *(f16*)(smem + S_E + esw(row, col * 2)) = (f16)e;
            }
        }
    }
#pragma unroll
    for (int ns = 0; ns < 4; ++ns) {
        colp[ns] += __shfl_xor(colp[ns], 16, 64);
        colp[ns] += __shfl_xor(colp[ns], 32, 64);
    }
    __syncthreads();
    if (tid < 128) CA[tid] = 0.f;
    __syncthreads();
    if (q == 0) {
#pragma unroll
        for (int ns = 0; ns < 4; ++ns)
            atomicAdd(&CA[wn + ns * 16 + lm], colp[ns]);
    }
    __syncthreads();
    if (tid < 128) atomicAdd(&S0g[col0 + tid], CA[tid]);
    gridbar(bar, 1);

    // ---------------- R/C passes: e-tile stays in registers ---------------
    const int rs = lane >> 3, cg = lane & 7;
    f16x8 e8[4][2];
    float u16r[16];

    // ---- R1 rows: u1 = 1/(K*S0); row partials -> R1g
    if (tid < 128) {
        float s = S0g[col0 + tid];
        Ul[tid] = (col0 + tid < KDIM) ? 1.0f / (1000.0f * s) : 0.0f;
    }
    __syncthreads();
#pragma unroll
    for (int i = 0; i < 16; ++i) u16r[i] = Ul[cg * 16 + i];
    {
        float pr[4];
#pragma unroll
        for (int j = 0; j < 4; ++j) {
            int row = wave * 32 + j * 8 + rs;
            e8[j][0] = *(const f16x8*)(smem + S_E + esw(row, cg * 32));
            e8[j][1] = *(const f16x8*)(smem + S_E + esw(row, cg * 32 + 16));
            float a0 = 0.f;
#pragma unroll
            for (int i = 0; i < 8; ++i)
                a0 += (float)e8[j][0][i] * u16r[i] + (float)e8[j][1][i] * u16r[8 + i];
            pr[j] = a0;
        }
#pragma unroll
        for (int m = 1; m <= 4; m <<= 1) {
            float t0 = __shfl_xor(pr[0], m, 64), t1 = __shfl_xor(pr[1], m, 64);
            float t2 = __shfl_xor(pr[2], m, 64), t3 = __shfl_xor(pr[3], m, 64);
            pr[0] += t0; pr[1] += t1; pr[2] += t2; pr[3] += t3;
        }
        if (cg == 0) {
#pragma unroll
            for (int j = 0; j < 4; ++j)
                atomicAdd(&R1g[rowbase + wave * 32 + j * 8 + rs], pr[j]);
        }
    }
    gridbar(bar, 2);

    // ---- R1 cols: v1 = 1/(B*rowsum); col partials -> S1g
    if (tid < 128) Vl[tid] = 1.0f / (12288.0f * R1g[rowbase + tid]);
    __syncthreads();
    {
        float ca[16];
#pragma unroll
        for (int i = 0; i < 16; ++i) ca[i] = 0.f;
#pragma unroll
        for (int j = 0; j < 4; ++j) {
            float vj = Vl[wave * 32 + j * 8 + rs];
#pragma unroll
            for (int i = 0; i < 8; ++i) {
                ca[i]     += (float)e8[j][0][i] * vj;
                ca[8 + i] += (float)e8[j][1][i] * vj;
            }
        }
#pragma unroll
        for (int m = 8; m <= 32; m <<= 1)
#pragma unroll
            for (int i = 0; i < 16; ++i) ca[i] += __shfl_xor(ca[i], m, 64);
        __syncthreads();
        if (tid < 128) CA[tid] = 0.f;
        __syncthreads();
        if (rs == 0) {
#pragma unroll
            for (int i = 0; i < 16; ++i) atomicAdd(&CA[cg * 16 + i], ca[i]);
        }
        __syncthreads();
        if (tid < 128) atomicAdd(&S1g[col0 + tid], CA[tid]);
    }
    gridbar(bar, 3);

    // ---- R2 rows: u2 = 1/(K*S1); row partials -> R2g
    if (tid < 128) {
        float s = S1g[col0 + tid];
        Ul[tid] = (col0 + tid < KDIM) ? 1.0f / (1000.0f * s) : 0.0f;
    }
    __syncthreads();
#pragma unroll
    for (int i = 0; i < 16; ++i) u16r[i] = Ul[cg * 16 + i];
    {
        float pr[4];
#pragma unroll
        for (int j = 0; j < 4; ++j) {
            float a0 = 0.f;
#pragma unroll
            for (int i = 0; i < 8; ++i)
                a0 += (float)e8[j][0][i] * u16r[i] + (float)e8[j][1][i] * u16r[8 + i];
            pr[j] = a0;
        }
#pragma unroll
        for (int m = 1; m <= 4; m <<= 1) {
            float t0 = __shfl_xor(pr[0], m, 64), t1 = __shfl_xor(pr[1], m, 64);
            float t2 = __shfl_xor(pr[2], m, 64), t3 = __shfl_xor(pr[3], m, 64);
            pr[0] += t0; pr[1] += t1; pr[2] += t2; pr[3] += t3;
        }
        if (cg == 0) {
#pragma unroll
            for (int j = 0; j < 4; ++j)
                atomicAdd(&R2g[rowbase + wave * 32 + j * 8 + rs], pr[j]);
        }
    }
    gridbar(bar, 4);

    // ---- R2 cols: v2; col partials -> S2g
    if (tid < 128) Vl[tid] = 1.0f / (12288.0f * R2g[rowbase + tid]);
    __syncthreads();
    {
        float ca[16];
#pragma unroll
        for (int i = 0; i < 16; ++i) ca[i] = 0.f;
#pragma unroll
        for (int j = 0; j < 4; ++j) {
            float vj = Vl[wave * 32 + j * 8 + rs];
#pragma unroll
            for (int i = 0; i < 8; ++i) {
                ca[i]     += (float)e8[j][0][i] * vj;
                ca[8 + i] += (float)e8[j][1][i] * vj;
            }
        }
#pragma unroll
        for (int m = 8; m <= 32; m <<= 1)
#pragma unroll
            for (int i = 0; i < 16; ++i) ca[i] += __shfl_xor(ca[i], m, 64);
        __syncthreads();
        if (tid < 128) CA[tid] = 0.f;
        __syncthreads();
        if (rs == 0) {
#pragma unroll
            for (int i = 0; i < 16; ++i) atomicAdd(&CA[cg * 16 + i], ca[i]);
        }
        __syncthreads();
        if (tid < 128) atomicAdd(&S2g[col0 + tid], CA[tid]);
    }
    gridbar(bar, 5);

    // ---- OUT rows (feats rows only): u3 = 1/(K*S2); row partials -> R3g
    if (by < 32) {
        if (tid < 128) {
            float s = S2g[col0 + tid];
            Ul[tid] = (col0 + tid < KDIM) ? 1.0f / (1000.0f * s) : 0.0f;
        }
        __syncthreads();
#pragma unroll
        for (int i = 0; i < 16; ++i) u16r[i] = Ul[cg * 16 + i];
        float pr[4];
#pragma unroll
        for (int j = 0; j < 4; ++j) {
            float a0 = 0.f;
#pragma unroll
            for (int i = 0; i < 8; ++i)
                a0 += (float)e8[j][0][i] * u16r[i] + (float)e8[j][1][i] * u16r[8 + i];
            pr[j] = a0;
        }
#pragma unroll
        for (int m = 1; m <= 4; m <<= 1) {
            float t0 = __shfl_xor(pr[0], m, 64), t1 = __shfl_xor(pr[1], m, 64);
            float t2 = __shfl_xor(pr[2], m, 64), t3 = __shfl_xor(pr[3], m, 64);
            pr[0] += t0; pr[1] += t1; pr[2] += t2; pr[3] += t3;
        }
        if (cg == 0) {
#pragma unroll
            for (int j = 0; j < 4; ++j)
                atomicAdd(&R3g[rowbase + wave * 32 + j * 8 + rs], pr[j]);
        }
    }
    gridbar(bar, 6);

    // ---- OUT store: out = E*u3 / rowsum
    if (by < 32) {
        if (tid < 128) Vl[tid] = 1.0f / R3g[rowbase + tid];
        __syncthreads();
#pragma unroll
        for (int j = 0; j < 4; ++j) {
            int row = wave * 32 + j * 8 + rs;
            float inv = Vl[row];
            float w[16];
#pragma unroll
            for (int i = 0; i < 8; ++i) {
                w[i]     = (float)e8[j][0][i] * u16r[i] * inv;
                w[8 + i] = (float)e8[j][1][i] * u16r[8 + i] * inv;
            }
            float* orow = out + (size_t)(rowbase + row) * KDIM;
#pragma unroll
            for (int i4 = 0; i4 < 4; ++i4) {
                int c = cg * 16 + i4 * 4;
                int gc = col0 + c;
                if (gc + 3 < KDIM) {   // KDIM % 4 == 0: float4 fully valid or fully out
                    float4 o = { w[i4*4], w[i4*4+1], w[i4*4+2], w[i4*4+3] };
                    *(float4*)(orow + gc) = o;
                }
            }
        }
    }
}

// ===========================================================================
// Fallback: proven 5-kernel pipeline (145 µs), used if cooperative launch
// is rejected (e.g. occupancy validation fails).
// ===========================================================================
__global__ __launch_bounds__(256)
void prep_k(const float* __restrict__ feats, const float* __restrict__ queue,
            const float* __restrict__ head, f16* __restrict__ A16,
            f16* __restrict__ Bf, float* __restrict__ slabs) {
    int b = blockIdx.x, tid = threadIdx.x;
    int wave = tid >> 6, lane = tid & 63;
    if (b < 3072) {
        int row = b * 4 + wave;
        const float* src = (row < NFEAT) ? feats + (size_t)row * DDIM
                                         : queue + (size_t)(row - NFEAT) * DDIM;
        float4 v = *(const float4*)(src + lane * 4);
        float s = wsum(v.x * v.x + v.y * v.y + v.z * v.z + v.w * v.w);
        float inv = 1.0f / sqrtf(fmaxf(s, 1e-24f));
        f16x4 o = { (f16)(v.x * inv), (f16)(v.y * inv), (f16)(v.z * inv), (f16)(v.w * inv) };
        *(f16x4*)(A16 + (size_t)row * DDIM + lane * 4) = o;
    } else if (b < 3104) {
        __shared__ float rin[8];
        int kb = (b - 3072) * 8;
        for (int j = 0; j < 2; ++j) {
            int k = kb + wave * 2 + j;
            const float* hr = head + (size_t)k * KDIM;
            float s = 0.f;
            for (int n = lane; n < KDIM; n += 64) { float v = hr[n]; s += v * v; }
            s = wsum(s);
            if (lane == 0) rin[wave * 2 + j] = 1.0f / sqrtf(fmaxf(s, 1e-24f));
        }
        __syncthreads();
        float r[8];
#pragma unroll
        for (int i = 0; i < 8; ++i) r[i] = rin[i];
        for (int n = tid; n < KDIM; n += 256) {
            f16 tmp[8];
#pragma unroll
            for (int i = 0; i < 8; ++i)
                tmp[i] = (f16)(head[(size_t)(kb + i) * KDIM + n] * r[i]);
            *(uint4*)(Bf + (size_t)n * DDIM + kb) = *(const uint4*)(tmp);
        }
    } else {
        float* dst = slabs + (size_t)(b - 3104) * KPAD + tid * 4;
        *(float4*)dst = make_float4(0.f, 0.f, 0.f, 0.f);
    }
}

__global__ __launch_bounds__(256, 3)
void gemm_exp_k(const f16* __restrict__ A16, const f16* __restrict__ Bf,
                f16* __restrict__ E16, float* __restrict__ S0sl) {
    __shared__ __align__(16) char smem[34816];
    f16 (*Es)[136] = (f16(*)[136])smem;
    int tid = threadIdx.x;
    int wave = tid >> 6, lane = tid & 63;
    int lm = lane & 15, q = lane >> 4;
    int row0 = blockIdx.y * 128, col0 = blockIdx.x * 128;
    int wm = (wave >> 1) * 64, wn = (wave & 1) * 64;
    const f16* Ab = A16 + (size_t)(row0 + wm + lm) * DDIM + q * 8;
    const f16* Bb = Bf  + (size_t)(col0 + wn + lm) * DDIM + q * 8;

    f32x4 acc[4][4];
#pragma unroll
    for (int i = 0; i < 4; ++i)
#pragma unroll
        for (int j = 0; j < 4; ++j) acc[i][j] = (f32x4){0.f, 0.f, 0.f, 0.f};

#pragma unroll
    for (int kt = 0; kt < DDIM; kt += 32) {
        f16x8 a[4], b[4];
#pragma unroll
        for (int ms = 0; ms < 4; ++ms) a[ms] = *(const f16x8*)(Ab + (size_t)ms * 16 * DDIM + kt);
#pragma unroll
        for (int ns = 0; ns < 4; ++ns) b[ns] = *(const f16x8*)(Bb + (size_t)ns * 16 * DDIM + kt);
#pragma unroll
        for (int ms = 0; ms < 4; ++ms)
#pragma unroll
            for (int ns = 0; ns < 4; ++ns)
                acc[ms][ns] = __builtin_amdgcn_mfma_f32_16x16x32_f16(a[ms], b[ns], acc[ms][ns], 0, 0, 0);
    }

    float colp[4] = {0.f, 0.f, 0.f, 0.f};
#pragma unroll
    for (int ms = 0; ms < 4; ++ms) {
#pragma unroll
        for (int ns = 0; ns < 4; ++ns) {
            int gc = col0 + wn + ns * 16 + lm;
            bool ok = gc < KDIM;
#pragma unroll
            for (int r = 0; r < 4; ++r) {
                float e = ok ? __expf(acc[ms][ns][r] * 20.0f) : 0.0f;
                colp[ns] += e;
                Es[wm + ms * 16 + q * 4 + r][wn + ns * 16 + lm] = (f16)e;
            }
        }
    }
#pragma unroll
    for (int ns = 0; ns < 4; ++ns) {
        colp[ns] += __shfl_xor(colp[ns], 16, 64);
        colp[ns] += __shfl_xor(colp[ns], 32, 64);
    }
    __syncthreads();
    {
        int r = tid >> 1, half = tid & 1;
        const f16* src = &Es[r][half * 64];
        f16* dst = E16 + (size_t)(row0 + r) * KPAD + col0 + half * 64;
#pragma unroll
        for (int i = 0; i < 8; ++i)
            *(uint4*)(dst + i * 8) = *(const uint4*)(src + i * 8);
    }
    __syncthreads();
    float* cred = (float*)smem;
    if (tid < 128) cred[tid] = 0.f;
    __syncthreads();
    if (lane < 16) {
#pragma unroll
        for (int ns = 0; ns < 4; ++ns)
            atomicAdd(&cred[wn + ns * 16 + lane], colp[ns]);
    }
    __syncthreads();
    if (tid < 128)
        atomicAdd(&S0sl[(size_t)(blockIdx.y & 7) * KPAD + col0 + tid], cred[tid]);
}

__global__ __launch_bounds__(256)
void rowpass_k(const f16* __restrict__ E16, const float* __restrict__ SinSl,
               float* __restrict__ SoutSl) {
    __shared__ float rl[KPAD];
    __shared__ float cols4[4][KPAD];
    int tid = threadIdx.x, bid = blockIdx.x;
    {
        int n = tid * 4;
        float4 s = *(const float4*)(SinSl + n);
#pragma unroll
        for (int j = 1; j < NSLAB; ++j) {
            float4 t = *(const float4*)(SinSl + (size_t)j * KPAD + n);
            s.x += t.x; s.y += t.y; s.z += t.z; s.w += t.w;
        }
        float4 o;
        o.x = (n + 0 < KDIM) ? 1.0f / (1000.0f * s.x) : 0.0f;
        o.y = (n + 1 < KDIM) ? 1.0f / (1000.0f * s.y) : 0.0f;
        o.z = (n + 2 < KDIM) ? 1.0f / (1000.0f * s.z) : 0.0f;
        o.w = (n + 3 < KDIM) ? 1.0f / (1000.0f * s.w) : 0.0f;
        *(float4*)(rl + n) = o;
    }
    __syncthreads();
    int wave = tid >> 6, lane = tid & 63;
    int n0 = lane * 16;
    float rv[16];
#pragma unroll
    for (int i = 0; i < 16; ++i) rv[i] = rl[n0 + i];

    int rowbase = bid * 16 + wave * 4;
    const f16* erb = E16 + (size_t)rowbase * KPAD + n0;
    f16x8 e[4][2];
#pragma unroll
    for (int j = 0; j < 4; ++j) {
        e[j][0] = *(const f16x8*)(erb + (size_t)j * KPAD);
        e[j][1] = *(const f16x8*)(erb + (size_t)j * KPAD + 8);
    }
    float p[4];
#pragma unroll
    for (int j = 0; j < 4; ++j) {
        float acc = 0.f;
#pragma unroll
        for (int i = 0; i < 8; ++i) {
            acc += (float)e[j][0][i] * rv[i];
            acc += (float)e[j][1][i] * rv[8 + i];
        }
        p[j] = acc;
    }
#pragma unroll
    for (int m = 32; m >= 1; m >>= 1) {
        float t0 = __shfl_xor(p[0], m, 64);
        float t1 = __shfl_xor(p[1], m, 64);
        float t2 = __shfl_xor(p[2], m, 64);
        float t3 = __shfl_xor(p[3], m, 64);
        p[0] += t0; p[1] += t1; p[2] += t2; p[3] += t3;
    }
    float c[4];
#pragma unroll
    for (int j = 0; j < 4; ++j) c[j] = 1.0f / (12288.0f * p[j]);
    float ca[16];
#pragma unroll
    for (int i = 0; i < 16; ++i) {
        int h = i >> 3, ii = i & 7;
        ca[i] = (float)e[0][h][ii] * c[0] + (float)e[1][h][ii] * c[1]
              + (float)e[2][h][ii] * c[2] + (float)e[3][h][ii] * c[3];
    }
#pragma unroll
    for (int i = 0; i < 16; ++i) {
        int idx = (i + lane) & 15;
        cols4[wave][n0 + idx] = ca[idx];
    }
    __syncthreads();
    float* outSlab = SoutSl + (size_t)(bid & 7) * KPAD;
    for (int n = tid; n < KPAD; n += 256)
        atomicAdd(&outSlab[n],
                  cols4[0][n] + cols4[1][n] + cols4[2][n] + cols4[3][n]);
}

__global__ __launch_bounds__(256)
void out_k(const f16* __restrict__ E16, const float* __restrict__ S2sl,
           float* __restrict__ out) {
    __shared__ float rl[KPAD];
    int tid = threadIdx.x;
    {
        int n = tid * 4;
        float4 s = *(const float4*)(S2sl + n);
#pragma unroll
        for (int j = 1; j < NSLAB; ++j) {
            float4 t = *(const float4*)(S2sl + (size_t)j * KPAD + n);
            s.x += t.x; s.y += t.y; s.z += t.z; s.w += t.w;
        }
        float4 o;
        o.x = (n + 0 < KDIM) ? 1.0f / (1000.0f * s.x) : 0.0f;
        o.y = (n + 1 < KDIM) ? 1.0f / (1000.0f * s.y) : 0.0f;
        o.z = (n + 2 < KDIM) ? 1.0f / (1000.0f * s.z) : 0.0f;
        o.w = (n + 3 < KDIM) ? 1.0f / (1000.0f * s.w) : 0.0f;
        *(float4*)(rl + n) = o;
    }
    __syncthreads();
    int wave = tid >> 6, lane = tid & 63;
    int n0 = lane * 16;
    float rv[16];
#pragma unroll
    for (int i = 0; i < 16; ++i) rv[i] = rl[n0 + i];
    int row = blockIdx.x * 4 + wave;
    const f16* er = E16 + (size_t)row * KPAD + n0;
    f16x8 e0 = *(const f16x8*)er;
    f16x8 e1 = *(const f16x8*)(er + 8);
    float w[16];
    float p = 0.f;
#pragma unroll
    for (int i = 0; i < 8; ++i) {
        w[i] = (float)e0[i] * rv[i];
        w[8 + i] = (float)e1[i] * rv[8 + i];
    }
#pragma unroll
    for (int i = 0; i < 16; ++i) p += w[i];
    p = wsum(p);
    float inv = 1.0f / p;
    float* orow = out + (size_t)row * KDIM;
#pragma unroll
    for (int i = 0; i < 16; i += 4) {
        int n = n0 + i;
        if (n + 3 < KDIM) {
            float4 o = { w[i] * inv, w[i + 1] * inv, w[i + 2] * inv, w[i + 3] * inv };
            *(float4*)(orow + n) = o;
        } else {
#pragma unroll
            for (int t = 0; t < 4; ++t)
                if (n + t < KDIM) orow[n + t] = w[i + t] * inv;
        }
    }
}

// ---------------------------------------------------------------------------
extern "C" void kernel_launch(void* const* d_in, const int* in_sizes, int n_in,
                              void* d_out, int out_size, void* d_ws, size_t ws_size,
                              hipStream_t stream) {
    (void)in_sizes; (void)n_in; (void)out_size; (void)ws_size;
    const float* feats = (const float*)d_in[0];   // [4096,256]
    const float* head  = (const float*)d_in[1];   // [256,1000]
    const float* queue = (const float*)d_in[2];   // [8192,256]
    float* out = (float*)d_out;                   // [4096,1000]
    char* ws = (char*)d_ws;

    // zero slabs / row-slabs / barrier (capture-legal, stream-ordered)
    hipMemsetAsync(d_ws, 0, F_ZERO, stream);

    void* args[] = { (void*)&feats, (void*)&queue, (void*)&head, (void*)&out, (void*)&ws };
    hipError_t err = hipLaunchCooperativeKernel((const void*)fused2_k, dim3(NBLK),
                                                dim3(256), (void**)args, 0, stream);
    if (err != hipSuccess) {
        // fallback: proven 5-kernel pipeline
        f16*   A16   = (f16*)(ws + OFF_A16);
        f16*   Bf    = (f16*)(ws + OFF_BF);
        f16*   E16   = (f16*)(ws + OFF_E16);
        float* slabs = (float*)(ws + OFF_SL);
        float* S0sl  = slabs;
        float* S1sl  = slabs + NSLAB * KPAD;
        float* S2sl  = slabs + 2 * NSLAB * KPAD;
        prep_k<<<3128, 256, 0, stream>>>(feats, queue, head, A16, Bf, slabs);
        gemm_exp_k<<<dim3(8, 96), 256, 0, stream>>>(A16, Bf, E16, S0sl);
        rowpass_k<<<768, 256, 0, stream>>>(E16, S0sl, S1sl);
        rowpass_k<<<768, 256, 0, stream>>>(E16, S1sl, S2sl);
        out_k<<<NFEAT / 4, 256, 0, stream>>>(E16, S2sl, out);
    }
}

// Round 3
// 251.927 us; speedup vs baseline: 1.9491x; 1.1401x over previous
//
#include <hip/hip_runtime.h>
#include <math.h>

typedef _Float16 f16;
typedef _Float16 f16x8 __attribute__((ext_vector_type(8)));
typedef _Float16 f16x4 __attribute__((ext_vector_type(4)));
typedef float f32x4 __attribute__((ext_vector_type(4)));

#define NROWS 12288
#define NFEAT 4096
#define DDIM  256
#define KDIM  1000
#define KPAD  1024
#define NSLAB 8
#define TAIL_NBLK 768

// workspace layout (bytes)
static const size_t OFF_A16 = 0;           // 12288*256 f16 = 6,291,456
static const size_t OFF_BF  = 6291456;     // 1024*256 f16  =   524,288
static const size_t OFF_E16 = 6815744;     // 12288*1024 f16= 25,165,824
static const size_t OFF_SL  = 31981568;    // 3 * 8 * 1024 f32 slabs, then 1 int counter

__device__ inline float wsum(float v) {
#pragma unroll
    for (int m = 32; m >= 1; m >>= 1) v += __shfl_xor(v, m, 64);
    return v;
}

// ---------------------------------------------------------------------------
// prep: [0,3072)   feats/queue row norms -> A16 (4 rows/block)
//       [3072,3104) head: 8 k-rows/block -> transposed normalized f16 Bf
//       [3104,3128) zero the 3 slab accumulators (+ tail barrier counter)
__global__ __launch_bounds__(256)
void prep_k(const float* __restrict__ feats, const float* __restrict__ queue,
            const float* __restrict__ head, f16* __restrict__ A16,
            f16* __restrict__ Bf, float* __restrict__ slabs) {
    int b = blockIdx.x, tid = threadIdx.x;
    int wave = tid >> 6, lane = tid & 63;
    if (b < 3072) {
        int row = b * 4 + wave;
        const float* src = (row < NFEAT) ? feats + (size_t)row * DDIM
                                         : queue + (size_t)(row - NFEAT) * DDIM;
        float4 v = *(const float4*)(src + lane * 4);
        float s = wsum(v.x * v.x + v.y * v.y + v.z * v.z + v.w * v.w);
        float inv = 1.0f / sqrtf(fmaxf(s, 1e-24f));
        f16x4 o = { (f16)(v.x * inv), (f16)(v.y * inv), (f16)(v.z * inv), (f16)(v.w * inv) };
        *(f16x4*)(A16 + (size_t)row * DDIM + lane * 4) = o;
    } else if (b < 3104) {
        __shared__ float rin[8];
        int kb = (b - 3072) * 8;
        for (int j = 0; j < 2; ++j) {
            int k = kb + wave * 2 + j;
            const float* hr = head + (size_t)k * KDIM;
            float s = 0.f;
            for (int n = lane; n < KDIM; n += 64) { float v = hr[n]; s += v * v; }
            s = wsum(s);
            if (lane == 0) rin[wave * 2 + j] = 1.0f / sqrtf(fmaxf(s, 1e-24f));
        }
        __syncthreads();
        float r[8];
#pragma unroll
        for (int i = 0; i < 8; ++i) r[i] = rin[i];
        for (int n = tid; n < KDIM; n += 256) {
            f16 tmp[8];
#pragma unroll
            for (int i = 0; i < 8; ++i)
                tmp[i] = (f16)(head[(size_t)(kb + i) * KDIM + n] * r[i]);
            *(uint4*)(Bf + (size_t)n * DDIM + kb) = *(const uint4*)(tmp);
        }
    } else {
        float* dst = slabs + (size_t)(b - 3104) * KPAD + tid * 4;
        *(float4*)dst = make_float4(0.f, 0.f, 0.f, 0.f);
        if (b == 3104 && tid == 0)
            ((int*)(slabs + 3 * NSLAB * KPAD))[0] = 0;   // tail barrier counter
    }
}

// ---------------------------------------------------------------------------
// MFMA GEMM + exp + f16 E store. 1-D grid with XCD swizzle: by = b%96,
// bx = b/96 -> the 8 blocks sharing an A-row-panel have b%8 == by%8, i.e.
// they co-locate on one XCD and share its L2 copy of the 64KB A panel
// (round-2 counters showed 8x duplicated fetch with the old mapping).
__global__ __launch_bounds__(256, 3)
void gemm_exp_k(const f16* __restrict__ A16, const f16* __restrict__ Bf,
                f16* __restrict__ E16, float* __restrict__ S0sl) {
    __shared__ __align__(16) char smem[34816];
    f16 (*Es)[136] = (f16(*)[136])smem;
    int tid = threadIdx.x;
    int wave = tid >> 6, lane = tid & 63;
    int lm = lane & 15, q = lane >> 4;
    int b = blockIdx.x;
    int by = b % 96, bx = b / 96;         // XCD-locality swizzle
    int row0 = by * 128, col0 = bx * 128;
    int wm = (wave >> 1) * 64, wn = (wave & 1) * 64;
    const f16* Ab = A16 + (size_t)(row0 + wm + lm) * DDIM + q * 8;
    const f16* Bb = Bf  + (size_t)(col0 + wn + lm) * DDIM + q * 8;

    f32x4 acc[4][4];
#pragma unroll
    for (int i = 0; i < 4; ++i)
#pragma unroll
        for (int j = 0; j < 4; ++j) acc[i][j] = (f32x4){0.f, 0.f, 0.f, 0.f};

#pragma unroll
    for (int kt = 0; kt < DDIM; kt += 32) {
        f16x8 a[4], bf[4];
#pragma unroll
        for (int ms = 0; ms < 4; ++ms) a[ms] = *(const f16x8*)(Ab + (size_t)ms * 16 * DDIM + kt);
#pragma unroll
        for (int ns = 0; ns < 4; ++ns) bf[ns] = *(const f16x8*)(Bb + (size_t)ns * 16 * DDIM + kt);
#pragma unroll
        for (int ms = 0; ms < 4; ++ms)
#pragma unroll
            for (int ns = 0; ns < 4; ++ns)
                acc[ms][ns] = __builtin_amdgcn_mfma_f32_16x16x32_f16(a[ms], bf[ns], acc[ms][ns], 0, 0, 0);
    }

    float colp[4] = {0.f, 0.f, 0.f, 0.f};
#pragma unroll
    for (int ms = 0; ms < 4; ++ms) {
#pragma unroll
        for (int ns = 0; ns < 4; ++ns) {
            int gc = col0 + wn + ns * 16 + lm;
            bool ok = gc < KDIM;
#pragma unroll
            for (int r = 0; r < 4; ++r) {
                float e = ok ? __expf(acc[ms][ns][r] * 20.0f) : 0.0f;
                colp[ns] += e;
                Es[wm + ms * 16 + q * 4 + r][wn + ns * 16 + lm] = (f16)e;
            }
        }
    }
#pragma unroll
    for (int ns = 0; ns < 4; ++ns) {
        colp[ns] += __shfl_xor(colp[ns], 16, 64);
        colp[ns] += __shfl_xor(colp[ns], 32, 64);
    }
    __syncthreads();
    {
        int r = tid >> 1, half = tid & 1;
        const f16* src = &Es[r][half * 64];
        f16* dst = E16 + (size_t)(row0 + r) * KPAD + col0 + half * 64;
#pragma unroll
        for (int i = 0; i < 8; ++i)
            *(uint4*)(dst + i * 8) = *(const uint4*)(src + i * 8);
    }
    __syncthreads();
    float* cred = (float*)smem;
    if (tid < 128) cred[tid] = 0.f;
    __syncthreads();
    if (lane < 16) {
#pragma unroll
        for (int ns = 0; ns < 4; ++ns)
            atomicAdd(&cred[wn + ns * 16 + lane], colp[ns]);   // LDS atomic
    }
    __syncthreads();
    if (tid < 128)
        atomicAdd(&S0sl[(size_t)(by & 7) * KPAD + col0 + tid], cred[tid]);
}

// ---------------------------------------------------------------------------
// Fused tail (cooperative, 768 blocks x 256): E strip (16 full rows) loaded
// to registers ONCE; row-sums are block-local; only column sums cross blocks
// (device-scope atomics). 2 monotonic-counter barriers replace 2 kernel
// boundaries + 33 MB of E16 re-reads. Blocks >=256 exit after barrier-2
// contribution; blocks 0..255 write out rows 0..4095.
__global__ __launch_bounds__(256)
void tail_k(const f16* __restrict__ E16, float* __restrict__ slabs,
            float* __restrict__ out) {
    __shared__ float rl[KPAD];
    __shared__ float cols4[4][KPAD];
    const int tid = threadIdx.x, b = blockIdx.x;
    const int wave = tid >> 6, lane = tid & 63;
    const int n0 = lane * 16;
    float* S0sl = slabs;
    float* S1sl = slabs + NSLAB * KPAD;
    float* S2sl = slabs + 2 * NSLAB * KPAD;
    int*   cnt  = (int*)(slabs + 3 * NSLAB * KPAD);

    // ---- u1 = 1/(K * colsum0)  (S0 slabs via kernel boundary: safe plain loads)
    {
        int n = tid * 4;
        float4 s = *(const float4*)(S0sl + n);
#pragma unroll
        for (int j = 1; j < NSLAB; ++j) {
            float4 t = *(const float4*)(S0sl + (size_t)j * KPAD + n);
            s.x += t.x; s.y += t.y; s.z += t.z; s.w += t.w;
        }
        float4 o;
        o.x = (n + 0 < KDIM) ? 1.0f / (1000.0f * s.x) : 0.0f;
        o.y = (n + 1 < KDIM) ? 1.0f / (1000.0f * s.y) : 0.0f;
        o.z = (n + 2 < KDIM) ? 1.0f / (1000.0f * s.z) : 0.0f;
        o.w = (n + 3 < KDIM) ? 1.0f / (1000.0f * s.w) : 0.0f;
        *(float4*)(rl + n) = o;
    }
    __syncthreads();
    float rv[16];
#pragma unroll
    for (int i = 0; i < 16; ++i) rv[i] = rl[n0 + i];

    const int rowbase = b * 16 + wave * 4;
    const f16* erb = E16 + (size_t)rowbase * KPAD + n0;
    f16x8 e[4][2];
#pragma unroll
    for (int j = 0; j < 4; ++j) {
        e[j][0] = *(const f16x8*)(erb + (size_t)j * KPAD);
        e[j][1] = *(const f16x8*)(erb + (size_t)j * KPAD + 8);
    }

    // ---- pass 1: block-local row sums -> c1; col partials -> S1
    {
        float p[4];
#pragma unroll
        for (int j = 0; j < 4; ++j) {
            float acc = 0.f;
#pragma unroll
            for (int i = 0; i < 8; ++i) {
                acc += (float)e[j][0][i] * rv[i];
                acc += (float)e[j][1][i] * rv[8 + i];
            }
            p[j] = acc;
        }
#pragma unroll
        for (int m = 32; m >= 1; m >>= 1) {
            float t0 = __shfl_xor(p[0], m, 64);
            float t1 = __shfl_xor(p[1], m, 64);
            float t2 = __shfl_xor(p[2], m, 64);
            float t3 = __shfl_xor(p[3], m, 64);
            p[0] += t0; p[1] += t1; p[2] += t2; p[3] += t3;
        }
        float c[4];
#pragma unroll
        for (int j = 0; j < 4; ++j) c[j] = 1.0f / (12288.0f * p[j]);
        float ca[16];
#pragma unroll
        for (int i = 0; i < 16; ++i) {
            int h = i >> 3, ii = i & 7;
            ca[i] = (float)e[0][h][ii] * c[0] + (float)e[1][h][ii] * c[1]
                  + (float)e[2][h][ii] * c[2] + (float)e[3][h][ii] * c[3];
        }
#pragma unroll
        for (int i = 0; i < 16; ++i) {
            int idx = (i + lane) & 15;
            cols4[wave][n0 + idx] = ca[idx];
        }
        __syncthreads();
        float* sl = S1sl + (size_t)(b & 7) * KPAD;
        for (int n = tid; n < KPAD; n += 256)
            atomicAdd(&sl[n], cols4[0][n] + cols4[1][n] + cols4[2][n] + cols4[3][n]);
    }

    // ---- barrier 1 (all 768 blocks)
    __syncthreads();     // drains each thread's atomics (vmcnt) before release
    if (tid == 0) {
        __hip_atomic_fetch_add(cnt, 1, __ATOMIC_RELEASE, __HIP_MEMORY_SCOPE_AGENT);
        while (__hip_atomic_load(cnt, __ATOMIC_RELAXED, __HIP_MEMORY_SCOPE_AGENT) < TAIL_NBLK)
            __builtin_amdgcn_s_sleep(4);
        __builtin_amdgcn_fence(__ATOMIC_ACQUIRE, "agent");
    }
    __syncthreads();

    // ---- u2 from S1 (atomics live at LLC; local L2 has no copy + acquire inv)
    {
        int n = tid * 4;
        float4 s = *(const float4*)(S1sl + n);
#pragma unroll
        for (int j = 1; j < NSLAB; ++j) {
            float4 t = *(const float4*)(S1sl + (size_t)j * KPAD + n);
            s.x += t.x; s.y += t.y; s.z += t.z; s.w += t.w;
        }
        float4 o;
        o.x = (n + 0 < KDIM) ? 1.0f / (1000.0f * s.x) : 0.0f;
        o.y = (n + 1 < KDIM) ? 1.0f / (1000.0f * s.y) : 0.0f;
        o.z = (n + 2 < KDIM) ? 1.0f / (1000.0f * s.z) : 0.0f;
        o.w = (n + 3 < KDIM) ? 1.0f / (1000.0f * s.w) : 0.0f;
        *(float4*)(rl + n) = o;
    }
    __syncthreads();
#pragma unroll
    for (int i = 0; i < 16; ++i) rv[i] = rl[n0 + i];

    // ---- pass 2
    {
        float p[4];
#pragma unroll
        for (int j = 0; j < 4; ++j) {
            float acc = 0.f;
#pragma unroll
            for (int i = 0; i < 8; ++i) {
                acc += (float)e[j][0][i] * rv[i];
                acc += (float)e[j][1][i] * rv[8 + i];
            }
            p[j] = acc;
        }
#pragma unroll
        for (int m = 32; m >= 1; m >>= 1) {
            float t0 = __shfl_xor(p[0], m, 64);
            float t1 = __shfl_xor(p[1], m, 64);
            float t2 = __shfl_xor(p[2], m, 64);
            float t3 = __shfl_xor(p[3], m, 64);
            p[0] += t0; p[1] += t1; p[2] += t2; p[3] += t3;
        }
        float c[4];
#pragma unroll
        for (int j = 0; j < 4; ++j) c[j] = 1.0f / (12288.0f * p[j]);
        float ca[16];
#pragma unroll
        for (int i = 0; i < 16; ++i) {
            int h = i >> 3, ii = i & 7;
            ca[i] = (float)e[0][h][ii] * c[0] + (float)e[1][h][ii] * c[1]
                  + (float)e[2][h][ii] * c[2] + (float)e[3][h][ii] * c[3];
        }
#pragma unroll
        for (int i = 0; i < 16; ++i) {
            int idx = (i + lane) & 15;
            cols4[wave][n0 + idx] = ca[idx];
        }
        __syncthreads();
        float* sl = S2sl + (size_t)(b & 7) * KPAD;
        for (int n = tid; n < KPAD; n += 256)
            atomicAdd(&sl[n], cols4[0][n] + cols4[1][n] + cols4[2][n] + cols4[3][n]);
    }

    // ---- barrier 2: everyone contributes; only out-blocks (b<256) wait
    __syncthreads();
    if (tid == 0)
        __hip_atomic_fetch_add(cnt, 1, __ATOMIC_RELEASE, __HIP_MEMORY_SCOPE_AGENT);
    if (b >= 256) return;
    if (tid == 0) {
        while (__hip_atomic_load(cnt, __ATOMIC_RELAXED, __HIP_MEMORY_SCOPE_AGENT) < 2 * TAIL_NBLK)
            __builtin_amdgcn_s_sleep(4);
        __builtin_amdgcn_fence(__ATOMIC_ACQUIRE, "agent");
    }
    __syncthreads();

    // ---- u3 from S2; out = E*u3 / rowsum   (rows 0..4095)
    {
        int n = tid * 4;
        float4 s = *(const float4*)(S2sl + n);
#pragma unroll
        for (int j = 1; j < NSLAB; ++j) {
            float4 t = *(const float4*)(S2sl + (size_t)j * KPAD + n);
            s.x += t.x; s.y += t.y; s.z += t.z; s.w += t.w;
        }
        float4 o;
        o.x = (n + 0 < KDIM) ? 1.0f / (1000.0f * s.x) : 0.0f;
        o.y = (n + 1 < KDIM) ? 1.0f / (1000.0f * s.y) : 0.0f;
        o.z = (n + 2 < KDIM) ? 1.0f / (1000.0f * s.z) : 0.0f;
        o.w = (n + 3 < KDIM) ? 1.0f / (1000.0f * s.w) : 0.0f;
        *(float4*)(rl + n) = o;
    }
    __syncthreads();
#pragma unroll
    for (int i = 0; i < 16; ++i) rv[i] = rl[n0 + i];

#pragma unroll
    for (int j = 0; j < 4; ++j) {
        float w[16];
        float p = 0.f;
#pragma unroll
        for (int i = 0; i < 8; ++i) {
            w[i]     = (float)e[j][0][i] * rv[i];
            w[8 + i] = (float)e[j][1][i] * rv[8 + i];
        }
#pragma unroll
        for (int i = 0; i < 16; ++i) p += w[i];
        p = wsum(p);
        float inv = 1.0f / p;
        float* orow = out + (size_t)(rowbase + j) * KDIM;
#pragma unroll
        for (int i = 0; i < 16; i += 4) {
            int n = n0 + i;
            if (n + 3 < KDIM) {       // KDIM%4==0: quad fully valid or fully out
                float4 o = { w[i] * inv, w[i + 1] * inv, w[i + 2] * inv, w[i + 3] * inv };
                *(float4*)(orow + n) = o;
            }
        }
    }
}

// ===========================================================================
// Fallback tail: proven rowpass x2 + out_k (used if cooperative launch fails)
// ===========================================================================
__global__ __launch_bounds__(256)
void rowpass_k(const f16* __restrict__ E16, const float* __restrict__ SinSl,
               float* __restrict__ SoutSl) {
    __shared__ float rl[KPAD];
    __shared__ float cols4[4][KPAD];
    int tid = threadIdx.x, bid = blockIdx.x;
    {
        int n = tid * 4;
        float4 s = *(const float4*)(SinSl + n);
#pragma unroll
        for (int j = 1; j < NSLAB; ++j) {
            float4 t = *(const float4*)(SinSl + (size_t)j * KPAD + n);
            s.x += t.x; s.y += t.y; s.z += t.z; s.w += t.w;
        }
        float4 o;
        o.x = (n + 0 < KDIM) ? 1.0f / (1000.0f * s.x) : 0.0f;
        o.y = (n + 1 < KDIM) ? 1.0f / (1000.0f * s.y) : 0.0f;
        o.z = (n + 2 < KDIM) ? 1.0f / (1000.0f * s.z) : 0.0f;
        o.w = (n + 3 < KDIM) ? 1.0f / (1000.0f * s.w) : 0.0f;
        *(float4*)(rl + n) = o;
    }
    __syncthreads();
    int wave = tid >> 6, lane = tid & 63;
    int n0 = lane * 16;
    float rv[16];
#pragma unroll
    for (int i = 0; i < 16; ++i) rv[i] = rl[n0 + i];

    int rowbase = bid * 16 + wave * 4;
    const f16* erb = E16 + (size_t)rowbase * KPAD + n0;
    f16x8 e[4][2];
#pragma unroll
    for (int j = 0; j < 4; ++j) {
        e[j][0] = *(const f16x8*)(erb + (size_t)j * KPAD);
        e[j][1] = *(const f16x8*)(erb + (size_t)j * KPAD + 8);
    }
    float p[4];
#pragma unroll
    for (int j = 0; j < 4; ++j) {
        float acc = 0.f;
#pragma unroll
        for (int i = 0; i < 8; ++i) {
            acc += (float)e[j][0][i] * rv[i];
            acc += (float)e[j][1][i] * rv[8 + i];
        }
        p[j] = acc;
    }
#pragma unroll
    for (int m = 32; m >= 1; m >>= 1) {
        float t0 = __shfl_xor(p[0], m, 64);
        float t1 = __shfl_xor(p[1], m, 64);
        float t2 = __shfl_xor(p[2], m, 64);
        float t3 = __shfl_xor(p[3], m, 64);
        p[0] += t0; p[1] += t1; p[2] += t2; p[3] += t3;
    }
    float c[4];
#pragma unroll
    for (int j = 0; j < 4; ++j) c[j] = 1.0f / (12288.0f * p[j]);
    float ca[16];
#pragma unroll
    for (int i = 0; i < 16; ++i) {
        int h = i >> 3, ii = i & 7;
        ca[i] = (float)e[0][h][ii] * c[0] + (float)e[1][h][ii] * c[1]
              + (float)e[2][h][ii] * c[2] + (float)e[3][h][ii] * c[3];
    }
#pragma unroll
    for (int i = 0; i < 16; ++i) {
        int idx = (i + lane) & 15;
        cols4[wave][n0 + idx] = ca[idx];
    }
    __syncthreads();
    float* outSlab = SoutSl + (size_t)(bid & 7) * KPAD;
    for (int n = tid; n < KPAD; n += 256)
        atomicAdd(&outSlab[n],
                  cols4[0][n] + cols4[1][n] + cols4[2][n] + cols4[3][n]);
}

__global__ __launch_bounds__(256)
void out_k(const f16* __restrict__ E16, const float* __restrict__ S2sl,
           float* __restrict__ out) {
    __shared__ float rl[KPAD];
    int tid = threadIdx.x;
    {
        int n = tid * 4;
        float4 s = *(const float4*)(S2sl + n);
#pragma unroll
        for (int j = 1; j < NSLAB; ++j) {
            float4 t = *(const float4*)(S2sl + (size_t)j * KPAD + n);
            s.x += t.x; s.y += t.y; s.z += t.z; s.w += t.w;
        }
        float4 o;
        o.x = (n + 0 < KDIM) ? 1.0f / (1000.0f * s.x) : 0.0f;
        o.y = (n + 1 < KDIM) ? 1.0f / (1000.0f * s.y) : 0.0f;
        o.z = (n + 2 < KDIM) ? 1.0f / (1000.0f * s.z) : 0.0f;
        o.w = (n + 3 < KDIM) ? 1.0f / (1000.0f * s.w) : 0.0f;
        *(float4*)(rl + n) = o;
    }
    __syncthreads();
    int wave = tid >> 6, lane = tid & 63;
    int n0 = lane * 16;
    float rv[16];
#pragma unroll
    for (int i = 0; i < 16; ++i) rv[i] = rl[n0 + i];
    int row = blockIdx.x * 4 + wave;
    const f16* er = E16 + (size_t)row * KPAD + n0;
    f16x8 e0 = *(const f16x8*)er;
    f16x8 e1 = *(const f16x8*)(er + 8);
    float w[16];
    float p = 0.f;
#pragma unroll
    for (int i = 0; i < 8; ++i) {
        w[i] = (float)e0[i] * rv[i];
        w[8 + i] = (float)e1[i] * rv[8 + i];
    }
#pragma unroll
    for (int i = 0; i < 16; ++i) p += w[i];
    p = wsum(p);
    float inv = 1.0f / p;
    float* orow = out + (size_t)row * KDIM;
#pragma unroll
    for (int i = 0; i < 16; i += 4) {
        int n = n0 + i;
        if (n + 3 < KDIM) {
            float4 o = { w[i] * inv, w[i + 1] * inv, w[i + 2] * inv, w[i + 3] * inv };
            *(float4*)(orow + n) = o;
        }
    }
}

// ---------------------------------------------------------------------------
extern "C" void kernel_launch(void* const* d_in, const int* in_sizes, int n_in,
                              void* d_out, int out_size, void* d_ws, size_t ws_size,
                              hipStream_t stream) {
    (void)in_sizes; (void)n_in; (void)out_size; (void)ws_size;
    const float* feats = (const float*)d_in[0];   // [4096,256]
    const float* head  = (const float*)d_in[1];   // [256,1000]
    const float* queue = (const float*)d_in[2];   // [8192,256]
    float* out = (float*)d_out;                   // [4096,1000]

    char* ws = (char*)d_ws;
    f16*   A16   = (f16*)(ws + OFF_A16);
    f16*   Bf    = (f16*)(ws + OFF_BF);
    f16*   E16   = (f16*)(ws + OFF_E16);
    float* slabs = (float*)(ws + OFF_SL);
    float* S0sl  = slabs;
    float* S1sl  = slabs + NSLAB * KPAD;
    float* S2sl  = slabs + 2 * NSLAB * KPAD;

    prep_k<<<3128, 256, 0, stream>>>(feats, queue, head, A16, Bf, slabs);
    gemm_exp_k<<<768, 256, 0, stream>>>(A16, Bf, E16, S0sl);

    const f16* E16c = E16;
    void* targs[] = { (void*)&E16c, (void*)&slabs, (void*)&out };
    hipError_t err = hipLaunchCooperativeKernel((const void*)tail_k, dim3(TAIL_NBLK),
                                                dim3(256), (void**)targs, 0, stream);
    if (err != hipSuccess) {
        rowpass_k<<<768, 256, 0, stream>>>(E16, S0sl, S1sl);
        rowpass_k<<<768, 256, 0, stream>>>(E16, S1sl, S2sl);
        out_k<<<NFEAT / 4, 256, 0, stream>>>(E16, S2sl, out);
    }
}

// Round 4
// 149.872 us; speedup vs baseline: 3.2764x; 1.6810x over previous
//
#include <hip/hip_runtime.h>
#include <math.h>

typedef _Float16 f16;
typedef _Float16 f16x8 __attribute__((ext_vector_type(8)));
typedef float f32x4 __attribute__((ext_vector_type(4)));

#define NROWS 12288
#define NFEAT 4096
#define DDIM  256
#define KDIM  1000
#define KPAD  1024
#define NSLAB 8

// workspace layout (bytes)
static const size_t OFF_BF  = 0;          // 1024*256 f16  =    524,288
static const size_t OFF_E16 = 524288;     // 12288*1024 f16= 25,165,824
static const size_t OFF_SL  = 25690112;   // 3 * 8 * 1024 f32 slabs

__device__ inline float wsum(float v) {
#pragma unroll
    for (int m = 32; m >= 1; m >>= 1) v += __shfl_xor(v, m, 64);
    return v;
}

// panel byte address (row stride 64 B) with bank swizzle; bijective,
// 16B-alignment preserving (XORs bits 4..6 only). Proven in round 2.
__device__ __forceinline__ int psw(int row, int bytecol) {
    return (row * 64 + bytecol) ^ ((row & 7) << 4);
}

// ---------------------------------------------------------------------------
// prep (56 blocks): [0,32)  head -> transposed normalized f16 Bf (8 k/block)
//                   [32,56) zero the 3 colsum slab sets
__global__ __launch_bounds__(256)
void prep_k(const float* __restrict__ head, f16* __restrict__ Bf,
            float* __restrict__ slabs) {
    int b = blockIdx.x, tid = threadIdx.x;
    int wave = tid >> 6, lane = tid & 63;
    if (b < 32) {
        __shared__ float rin[8];
        int kb = b * 8;
        for (int j = 0; j < 2; ++j) {
            int k = kb + wave * 2 + j;
            const float* hr = head + (size_t)k * KDIM;
            float s = 0.f;
            for (int n = lane; n < KDIM; n += 64) { float v = hr[n]; s += v * v; }
            s = wsum(s);
            if (lane == 0) rin[wave * 2 + j] = 1.0f / sqrtf(fmaxf(s, 1e-24f));
        }
        __syncthreads();
        float r[8];
#pragma unroll
        for (int i = 0; i < 8; ++i) r[i] = rin[i];
        for (int n = tid; n < KDIM; n += 256) {
            f16 tmp[8];
#pragma unroll
            for (int i = 0; i < 8; ++i)
                tmp[i] = (f16)(head[(size_t)(kb + i) * KDIM + n] * r[i]);
            *(uint4*)(Bf + (size_t)n * DDIM + kb) = *(const uint4*)(tmp);
        }
    } else {
        float* dst = slabs + (size_t)(b - 32) * KPAD + tid * 4;
        *(float4*)dst = make_float4(0.f, 0.f, 0.f, 0.f);
    }
}

// ---------------------------------------------------------------------------
// MFMA GEMM with fused A-normalization (feats/queue f32 read directly; no A16
// intermediate). 1-D grid, XCD swizzle: by = b%96, bx = b/96 -> the 8 blocks
// sharing an A-row-panel have b%8 == by%8 (co-located on one XCD; panel hits
// that XCD's L2 after the first fetch). Round-2 counters showed 8x duplicated
// HBM fetch with the default mapping.
// LDS: double-buffered A panels [2][128][32] f16 (psw-swizzled) union'd with
// the post-loop E tile Es[128][136]; rinv[128] f32 above both.
__global__ __launch_bounds__(256, 3)
void gemm_exp_k(const float* __restrict__ feats, const float* __restrict__ queue,
                const f16* __restrict__ Bf, f16* __restrict__ E16,
                float* __restrict__ S0sl) {
    __shared__ __align__(16) char smem[35328];
    f16 (*Es)[136] = (f16(*)[136])smem;
    float* rinv = (float*)(smem + 34816);
    const int tid = threadIdx.x;
    const int wave = tid >> 6, lane = tid & 63;
    const int lm = lane & 15, q = lane >> 4;
    const int b = blockIdx.x;
    const int by = b % 96, bx = b / 96;        // XCD-locality swizzle
    const int row0 = by * 128, col0 = bx * 128;
    const int wm = (wave >> 1) * 64, wn = (wave & 1) * 64;

    // per-thread staging assignment: row r, half h
    const int r = tid >> 1, h = tid & 1;
    const int grow = row0 + r;
    const float* srow = (grow < NFEAT) ? feats + (size_t)grow * DDIM
                                       : queue + (size_t)(grow - NFEAT) * DDIM;

    // ---- norm prepass: each thread sums squares of 128 elems; pair-combine
    {
        const float* p = srow + h * 128;
        float s = 0.f;
#pragma unroll
        for (int i = 0; i < 32; ++i) {
            float4 v = *(const float4*)(p + i * 4);
            s += v.x * v.x + v.y * v.y + v.z * v.z + v.w * v.w;
        }
        s += __shfl_xor(s, 1, 64);     // threads 2r / 2r+1 are adjacent lanes
        if (h == 0) rinv[r] = 1.0f / sqrtf(fmaxf(s, 1e-24f));
    }
    __syncthreads();
    const float sc = rinv[r];

    const f16* Bb = Bf + (size_t)(col0 + wn + lm) * DDIM + q * 8;

    f32x4 acc[4][4];
#pragma unroll
    for (int i = 0; i < 4; ++i)
#pragma unroll
        for (int j = 0; j < 4; ++j) acc[i][j] = (f32x4){0.f, 0.f, 0.f, 0.f};

    // ---- stage tile 0 into buffer 0
    {
        const float* p = srow + h * 16;
        float4 v0 = ((const float4*)p)[0];
        float4 v1 = ((const float4*)p)[1];
        float4 v2 = ((const float4*)p)[2];
        float4 v3 = ((const float4*)p)[3];
        f16 tmp[16];
        tmp[0]=(f16)(v0.x*sc); tmp[1]=(f16)(v0.y*sc); tmp[2]=(f16)(v0.z*sc); tmp[3]=(f16)(v0.w*sc);
        tmp[4]=(f16)(v1.x*sc); tmp[5]=(f16)(v1.y*sc); tmp[6]=(f16)(v1.z*sc); tmp[7]=(f16)(v1.w*sc);
        tmp[8]=(f16)(v2.x*sc); tmp[9]=(f16)(v2.y*sc); tmp[10]=(f16)(v2.z*sc); tmp[11]=(f16)(v2.w*sc);
        tmp[12]=(f16)(v3.x*sc); tmp[13]=(f16)(v3.y*sc); tmp[14]=(f16)(v3.z*sc); tmp[15]=(f16)(v3.w*sc);
        *(uint4*)(smem + psw(r, h * 32))      = ((const uint4*)tmp)[0];
        *(uint4*)(smem + psw(r, h * 32 + 16)) = ((const uint4*)tmp)[1];
    }
    __syncthreads();

    // ---- K loop, double-buffered panels (1 barrier per tile).
    // Hazard proof: stage(t+1) overwrites the buffer whose last reads happened
    // in iter t-1 before that iteration's barrier.
#pragma unroll
    for (int t = 0; t < 8; ++t) {
        char* PA = smem + (t & 1) * 8192;
        f16x8 a[4], bfr[4];
#pragma unroll
        for (int ms = 0; ms < 4; ++ms)
            a[ms] = *(const f16x8*)(PA + psw(wm + ms * 16 + lm, q * 16));
#pragma unroll
        for (int ns = 0; ns < 4; ++ns)
            bfr[ns] = *(const f16x8*)(Bb + (size_t)ns * 16 * DDIM + t * 32);
        if (t < 7) {
            char* PN = smem + ((t + 1) & 1) * 8192;
            const float* p = srow + (t + 1) * 32 + h * 16;
            float4 v0 = ((const float4*)p)[0];
            float4 v1 = ((const float4*)p)[1];
            float4 v2 = ((const float4*)p)[2];
            float4 v3 = ((const float4*)p)[3];
            f16 tmp[16];
            tmp[0]=(f16)(v0.x*sc); tmp[1]=(f16)(v0.y*sc); tmp[2]=(f16)(v0.z*sc); tmp[3]=(f16)(v0.w*sc);
            tmp[4]=(f16)(v1.x*sc); tmp[5]=(f16)(v1.y*sc); tmp[6]=(f16)(v1.z*sc); tmp[7]=(f16)(v1.w*sc);
            tmp[8]=(f16)(v2.x*sc); tmp[9]=(f16)(v2.y*sc); tmp[10]=(f16)(v2.z*sc); tmp[11]=(f16)(v2.w*sc);
            tmp[12]=(f16)(v3.x*sc); tmp[13]=(f16)(v3.y*sc); tmp[14]=(f16)(v3.z*sc); tmp[15]=(f16)(v3.w*sc);
            *(uint4*)(PN + psw(r, h * 32))      = ((const uint4*)tmp)[0];
            *(uint4*)(PN + psw(r, h * 32 + 16)) = ((const uint4*)tmp)[1];
        }
        __syncthreads();
#pragma unroll
        for (int ms = 0; ms < 4; ++ms)
#pragma unroll
            for (int ns = 0; ns < 4; ++ns)
                acc[ms][ns] = __builtin_amdgcn_mfma_f32_16x16x32_f16(a[ms], bfr[ns], acc[ms][ns], 0, 0, 0);
    }
    // all panel ds_reads completed before the last barrier; Es may reuse smem.

    // ---- exp + Es + colsum partials (round-0 proven epilogue)
    float colp[4] = {0.f, 0.f, 0.f, 0.f};
#pragma unroll
    for (int ms = 0; ms < 4; ++ms) {
#pragma unroll
        for (int ns = 0; ns < 4; ++ns) {
            int gc = col0 + wn + ns * 16 + lm;
            bool ok = gc < KDIM;
#pragma unroll
            for (int rr = 0; rr < 4; ++rr) {
                float e = ok ? __expf(acc[ms][ns][rr] * 20.0f) : 0.0f;
                colp[ns] += e;
                Es[wm + ms * 16 + q * 4 + rr][wn + ns * 16 + lm] = (f16)e;
            }
        }
    }
#pragma unroll
    for (int ns = 0; ns < 4; ++ns) {
        colp[ns] += __shfl_xor(colp[ns], 16, 64);
        colp[ns] += __shfl_xor(colp[ns], 32, 64);
    }
    __syncthreads();
    {
        int rr = tid >> 1, half = tid & 1;
        const f16* src = &Es[rr][half * 64];
        f16* dst = E16 + (size_t)(row0 + rr) * KPAD + col0 + half * 64;
#pragma unroll
        for (int i = 0; i < 8; ++i)
            *(uint4*)(dst + i * 8) = *(const uint4*)(src + i * 8);
    }
    __syncthreads();
    float* cred = (float*)smem;
    if (tid < 128) cred[tid] = 0.f;
    __syncthreads();
    if (lane < 16) {
#pragma unroll
        for (int ns = 0; ns < 4; ++ns)
            atomicAdd(&cred[wn + ns * 16 + lane], colp[ns]);   // LDS atomic
    }
    __syncthreads();
    if (tid < 128)
        atomicAdd(&S0sl[(size_t)(by & 7) * KPAD + col0 + tid], cred[tid]);
}

// ---------------------------------------------------------------------------
// rowpass (proven round-0): row sums block-local, column partials -> slabs.
__global__ __launch_bounds__(256)
void rowpass_k(const f16* __restrict__ E16, const float* __restrict__ SinSl,
               float* __restrict__ SoutSl) {
    __shared__ float rl[KPAD];
    __shared__ float cols4[4][KPAD];
    int tid = threadIdx.x, bid = blockIdx.x;
    {
        int n = tid * 4;
        float4 s = *(const float4*)(SinSl + n);
#pragma unroll
        for (int j = 1; j < NSLAB; ++j) {
            float4 t = *(const float4*)(SinSl + (size_t)j * KPAD + n);
            s.x += t.x; s.y += t.y; s.z += t.z; s.w += t.w;
        }
        float4 o;
        o.x = (n + 0 < KDIM) ? 1.0f / (1000.0f * s.x) : 0.0f;
        o.y = (n + 1 < KDIM) ? 1.0f / (1000.0f * s.y) : 0.0f;
        o.z = (n + 2 < KDIM) ? 1.0f / (1000.0f * s.z) : 0.0f;
        o.w = (n + 3 < KDIM) ? 1.0f / (1000.0f * s.w) : 0.0f;
        *(float4*)(rl + n) = o;
    }
    __syncthreads();
    int wave = tid >> 6, lane = tid & 63;
    int n0 = lane * 16;
    float rv[16];
#pragma unroll
    for (int i = 0; i < 16; ++i) rv[i] = rl[n0 + i];

    int rowbase = bid * 16 + wave * 4;
    const f16* erb = E16 + (size_t)rowbase * KPAD + n0;
    f16x8 e[4][2];
#pragma unroll
    for (int j = 0; j < 4; ++j) {
        e[j][0] = *(const f16x8*)(erb + (size_t)j * KPAD);
        e[j][1] = *(const f16x8*)(erb + (size_t)j * KPAD + 8);
    }
    float p[4];
#pragma unroll
    for (int j = 0; j < 4; ++j) {
        float acc = 0.f;
#pragma unroll
        for (int i = 0; i < 8; ++i) {
            acc += (float)e[j][0][i] * rv[i];
            acc += (float)e[j][1][i] * rv[8 + i];
        }
        p[j] = acc;
    }
#pragma unroll
    for (int m = 32; m >= 1; m >>= 1) {
        float t0 = __shfl_xor(p[0], m, 64);
        float t1 = __shfl_xor(p[1], m, 64);
        float t2 = __shfl_xor(p[2], m, 64);
        float t3 = __shfl_xor(p[3], m, 64);
        p[0] += t0; p[1] += t1; p[2] += t2; p[3] += t3;
    }
    float c[4];
#pragma unroll
    for (int j = 0; j < 4; ++j) c[j] = 1.0f / (12288.0f * p[j]);
    float ca[16];
#pragma unroll
    for (int i = 0; i < 16; ++i) {
        int h = i >> 3, ii = i & 7;
        ca[i] = (float)e[0][h][ii] * c[0] + (float)e[1][h][ii] * c[1]
              + (float)e[2][h][ii] * c[2] + (float)e[3][h][ii] * c[3];
    }
#pragma unroll
    for (int i = 0; i < 16; ++i) {
        int idx = (i + lane) & 15;
        cols4[wave][n0 + idx] = ca[idx];
    }
    __syncthreads();
    float* outSlab = SoutSl + (size_t)(bid & 7) * KPAD;
    for (int n = tid; n < KPAD; n += 256)
        atomicAdd(&outSlab[n],
                  cols4[0][n] + cols4[1][n] + cols4[2][n] + cols4[3][n]);
}

__global__ __launch_bounds__(256)
void out_k(const f16* __restrict__ E16, const float* __restrict__ S2sl,
           float* __restrict__ out) {
    __shared__ float rl[KPAD];
    int tid = threadIdx.x;
    {
        int n = tid * 4;
        float4 s = *(const float4*)(S2sl + n);
#pragma unroll
        for (int j = 1; j < NSLAB; ++j) {
            float4 t = *(const float4*)(S2sl + (size_t)j * KPAD + n);
            s.x += t.x; s.y += t.y; s.z += t.z; s.w += t.w;
        }
        float4 o;
        o.x = (n + 0 < KDIM) ? 1.0f / (1000.0f * s.x) : 0.0f;
        o.y = (n + 1 < KDIM) ? 1.0f / (1000.0f * s.y) : 0.0f;
        o.z = (n + 2 < KDIM) ? 1.0f / (1000.0f * s.z) : 0.0f;
        o.w = (n + 3 < KDIM) ? 1.0f / (1000.0f * s.w) : 0.0f;
        *(float4*)(rl + n) = o;
    }
    __syncthreads();
    int wave = tid >> 6, lane = tid & 63;
    int n0 = lane * 16;
    float rv[16];
#pragma unroll
    for (int i = 0; i < 16; ++i) rv[i] = rl[n0 + i];
    int row = blockIdx.x * 4 + wave;
    const f16* er = E16 + (size_t)row * KPAD + n0;
    f16x8 e0 = *(const f16x8*)er;
    f16x8 e1 = *(const f16x8*)(er + 8);
    float w[16];
    float p = 0.f;
#pragma unroll
    for (int i = 0; i < 8; ++i) {
        w[i] = (float)e0[i] * rv[i];
        w[8 + i] = (float)e1[i] * rv[8 + i];
    }
#pragma unroll
    for (int i = 0; i < 16; ++i) p += w[i];
    p = wsum(p);
    float inv = 1.0f / p;
    float* orow = out + (size_t)row * KDIM;
#pragma unroll
    for (int i = 0; i < 16; i += 4) {
        int n = n0 + i;
        if (n + 3 < KDIM) {   // KDIM%4==0: quad fully valid or fully out
            float4 o = { w[i] * inv, w[i + 1] * inv, w[i + 2] * inv, w[i + 3] * inv };
            *(float4*)(orow + n) = o;
        }
    }
}

// ---------------------------------------------------------------------------
extern "C" void kernel_launch(void* const* d_in, const int* in_sizes, int n_in,
                              void* d_out, int out_size, void* d_ws, size_t ws_size,
                              hipStream_t stream) {
    (void)in_sizes; (void)n_in; (void)out_size; (void)ws_size;
    const float* feats = (const float*)d_in[0];   // [4096,256]
    const float* head  = (const float*)d_in[1];   // [256,1000]
    const float* queue = (const float*)d_in[2];   // [8192,256]
    float* out = (float*)d_out;                   // [4096,1000]

    char* ws = (char*)d_ws;
    f16*   Bf    = (f16*)(ws + OFF_BF);
    f16*   E16   = (f16*)(ws + OFF_E16);
    float* slabs = (float*)(ws + OFF_SL);
    float* S0sl  = slabs;
    float* S1sl  = slabs + NSLAB * KPAD;
    float* S2sl  = slabs + 2 * NSLAB * KPAD;

    prep_k<<<56, 256, 0, stream>>>(head, Bf, slabs);
    gemm_exp_k<<<768, 256, 0, stream>>>(feats, queue, Bf, E16, S0sl);
    rowpass_k<<<768, 256, 0, stream>>>(E16, S0sl, S1sl);
    rowpass_k<<<768, 256, 0, stream>>>(E16, S1sl, S2sl);
    out_k<<<NFEAT / 4, 256, 0, stream>>>(E16, S2sl, out);
}

// Round 5
// 139.941 us; speedup vs baseline: 3.5089x; 1.0710x over previous
//
#include <hip/hip_runtime.h>
#include <math.h>

typedef _Float16 f16;
typedef _Float16 f16x8 __attribute__((ext_vector_type(8)));
typedef _Float16 f16x4 __attribute__((ext_vector_type(4)));
typedef float f32x4 __attribute__((ext_vector_type(4)));

#define NROWS 12288
#define NFEAT 4096
#define DDIM  256
#define KDIM  1000
#define KPAD  1024
#define NSLAB 8

// workspace layout (bytes)
static const size_t OFF_BF  = 0;          // 1024*256 f16  =    524,288
static const size_t OFF_E16 = 524288;     // 12288*1024 f16= 25,165,824
static const size_t OFF_SL  = 25690112;   // 3 * 8 * 1024 f32 slabs

__device__ inline float wsum(float v) {
#pragma unroll
    for (int m = 32; m >= 1; m >>= 1) v += __shfl_xor(v, m, 64);
    return v;
}

// panel byte address (row stride 64 B) with bank swizzle; bijective,
// 16B-alignment preserving (XORs bits 4..6 only).
__device__ __forceinline__ int psw(int row, int bytecol) {
    return (row * 64 + bytecol) ^ ((row & 7) << 4);
}

// ---------------------------------------------------------------------------
// prep (56 blocks): [0,32)  head -> transposed normalized f16 Bf (8 k/block)
//                   [32,56) zero the 3 colsum slab sets
__global__ __launch_bounds__(256)
void prep_k(const float* __restrict__ head, f16* __restrict__ Bf,
            float* __restrict__ slabs) {
    int b = blockIdx.x, tid = threadIdx.x;
    int wave = tid >> 6, lane = tid & 63;
    if (b < 32) {
        __shared__ float rin[8];
        int kb = b * 8;
        for (int j = 0; j < 2; ++j) {
            int k = kb + wave * 2 + j;
            const float* hr = head + (size_t)k * KDIM;
            float s = 0.f;
            for (int n = lane; n < KDIM; n += 64) { float v = hr[n]; s += v * v; }
            s = wsum(s);
            if (lane == 0) rin[wave * 2 + j] = 1.0f / sqrtf(fmaxf(s, 1e-24f));
        }
        __syncthreads();
        float r[8];
#pragma unroll
        for (int i = 0; i < 8; ++i) r[i] = rin[i];
        for (int n = tid; n < KDIM; n += 256) {
            f16 tmp[8];
#pragma unroll
            for (int i = 0; i < 8; ++i)
                tmp[i] = (f16)(head[(size_t)(kb + i) * KDIM + n] * r[i]);
            *(uint4*)(Bf + (size_t)n * DDIM + kb) = *(const uint4*)(tmp);
        }
    } else {
        float* dst = slabs + (size_t)(b - 32) * KPAD + tid * 4;
        *(float4*)dst = make_float4(0.f, 0.f, 0.f, 0.f);
    }
}

// ---------------------------------------------------------------------------
// MFMA GEMM, A read RAW from feats/queue f32 with COALESCED staging
// (thread -> row s*32+(tid>>3), cols (tid&7)*4: wave = 8x128B contiguous
// segments; round-4's tid>>1 layout fragmented every load into 64 segments).
// Row normalization commutes with the dot product, so it is folded into the
// epilogue: sumsq accumulates as a by-product of staging loads (same data,
// no prepass), and exp applies acc * (20*rinv_row).
// XCD swizzle by=b%96 (panel's 8 blocks share b%8 -> one XCD L2 copy).
__global__ __launch_bounds__(256, 3)
void gemm_exp_k(const float* __restrict__ feats, const float* __restrict__ queue,
                const f16* __restrict__ Bf, f16* __restrict__ E16,
                float* __restrict__ S0sl) {
    __shared__ __align__(16) char smem[35328];
    f16 (*Es)[136] = (f16(*)[136])smem;
    float* rinvl = (float*)(smem + 34816);
    const int tid = threadIdx.x;
    const int wave = tid >> 6, lane = tid & 63;
    const int lm = lane & 15, q = lane >> 4;
    const int b = blockIdx.x;
    const int by = b % 96, bx = b / 96;        // XCD-locality swizzle
    const int row0 = by * 128, col0 = bx * 128;
    const int wm = (wave >> 1) * 64, wn = (wave & 1) * 64;

    // staging assignment: sweep s -> row s*32+(tid>>3), float4 at col (tid&7)*4
    const float* rowptr[4];
#pragma unroll
    for (int s = 0; s < 4; ++s) {
        int grow = row0 + s * 32 + (tid >> 3);
        rowptr[s] = (grow < NFEAT) ? feats + (size_t)grow * DDIM
                                   : queue + (size_t)(grow - NFEAT) * DDIM;
    }
    float ss[4] = {0.f, 0.f, 0.f, 0.f};

    auto stage = [&](int tt, int buf) {
        char* P = smem + buf * 8192;
#pragma unroll
        for (int s = 0; s < 4; ++s) {
            float4 v = *(const float4*)(rowptr[s] + tt * 32 + (tid & 7) * 4);
            ss[s] += v.x * v.x + v.y * v.y + v.z * v.z + v.w * v.w;
            f16x4 tmp = { (f16)v.x, (f16)v.y, (f16)v.z, (f16)v.w };
            *(f16x4*)(P + psw(s * 32 + (tid >> 3), (tid & 7) * 8)) = tmp;
        }
    };

    const f16* Bb = Bf + (size_t)(col0 + wn + lm) * DDIM + q * 8;

    f32x4 acc[4][4];
#pragma unroll
    for (int i = 0; i < 4; ++i)
#pragma unroll
        for (int j = 0; j < 4; ++j) acc[i][j] = (f32x4){0.f, 0.f, 0.f, 0.f};

    stage(0, 0);
    __syncthreads();

    // K loop, double-buffered panels (1 barrier per tile). Hazard: stage(t+1)
    // overwrites the buffer last read in iter t-1, whose reads completed at
    // iter t-1's barrier.
#pragma unroll
    for (int t = 0; t < 8; ++t) {
        char* PA = smem + (t & 1) * 8192;
        f16x8 a[4], bfr[4];
#pragma unroll
        for (int ms = 0; ms < 4; ++ms)
            a[ms] = *(const f16x8*)(PA + psw(wm + ms * 16 + lm, q * 16));
#pragma unroll
        for (int ns = 0; ns < 4; ++ns)
            bfr[ns] = *(const f16x8*)(Bb + (size_t)ns * 16 * DDIM + t * 32);
        if (t < 7) stage(t + 1, (t + 1) & 1);
        __syncthreads();
#pragma unroll
        for (int ms = 0; ms < 4; ++ms)
#pragma unroll
            for (int ns = 0; ns < 4; ++ns)
                acc[ms][ns] = __builtin_amdgcn_mfma_f32_16x16x32_f16(a[ms], bfr[ns], acc[ms][ns], 0, 0, 0);
    }
    // all panel ds_reads completed before iter-7's barrier; Es may reuse smem.

    // ---- row inverse norms from staged sumsq: reduce over the 8 lanes
    // sharing a row (lane^1,2,4), write rinvl[128]
#pragma unroll
    for (int m = 1; m <= 4; m <<= 1) {
        ss[0] += __shfl_xor(ss[0], m, 64);
        ss[1] += __shfl_xor(ss[1], m, 64);
        ss[2] += __shfl_xor(ss[2], m, 64);
        ss[3] += __shfl_xor(ss[3], m, 64);
    }
    if ((lane & 7) == 0) {
#pragma unroll
        for (int s = 0; s < 4; ++s)
            rinvl[s * 32 + (tid >> 3)] = 1.0f / sqrtf(fmaxf(ss[s], 1e-24f));
    }
    __syncthreads();

    float rsc[4][4];
#pragma unroll
    for (int ms = 0; ms < 4; ++ms)
#pragma unroll
        for (int rr = 0; rr < 4; ++rr)
            rsc[ms][rr] = 20.0f * rinvl[wm + ms * 16 + q * 4 + rr];

    // ---- exp + Es + colsum partials (proven epilogue; scale now per-row)
    float colp[4] = {0.f, 0.f, 0.f, 0.f};
#pragma unroll
    for (int ms = 0; ms < 4; ++ms) {
#pragma unroll
        for (int ns = 0; ns < 4; ++ns) {
            int gc = col0 + wn + ns * 16 + lm;
            bool ok = gc < KDIM;
#pragma unroll
            for (int rr = 0; rr < 4; ++rr) {
                float e = ok ? __expf(acc[ms][ns][rr] * rsc[ms][rr]) : 0.0f;
                colp[ns] += e;
                Es[wm + ms * 16 + q * 4 + rr][wn + ns * 16 + lm] = (f16)e;
            }
        }
    }
#pragma unroll
    for (int ns = 0; ns < 4; ++ns) {
        colp[ns] += __shfl_xor(colp[ns], 16, 64);
        colp[ns] += __shfl_xor(colp[ns], 32, 64);
    }
    __syncthreads();
    {
        int rr = tid >> 1, half = tid & 1;
        const f16* src = &Es[rr][half * 64];
        f16* dst = E16 + (size_t)(row0 + rr) * KPAD + col0 + half * 64;
#pragma unroll
        for (int i = 0; i < 8; ++i)
            *(uint4*)(dst + i * 8) = *(const uint4*)(src + i * 8);
    }
    __syncthreads();
    float* cred = (float*)smem;
    if (tid < 128) cred[tid] = 0.f;
    __syncthreads();
    if (lane < 16) {
#pragma unroll
        for (int ns = 0; ns < 4; ++ns)
            atomicAdd(&cred[wn + ns * 16 + lane], colp[ns]);   // LDS atomic
    }
    __syncthreads();
    if (tid < 128)
        atomicAdd(&S0sl[(size_t)(by & 7) * KPAD + col0 + tid], cred[tid]);
}

// ---------------------------------------------------------------------------
// rowpass: XCD-aligned block remap. gemm panel p was written by XCD p%8;
// block bid (XCD bid%8) reads strip s of a panel p with p%8 == bid%8, so
// E reads hit the local L2 instead of crossing XCDs. Bijective:
// (x, i%12, i/12) <-> (p, s), 8*12*8 = 768.
__global__ __launch_bounds__(256)
void rowpass_k(const f16* __restrict__ E16, const float* __restrict__ SinSl,
               float* __restrict__ SoutSl) {
    __shared__ float rl[KPAD];
    __shared__ float cols4[4][KPAD];
    int tid = threadIdx.x, bid = blockIdx.x;
    {
        int n = tid * 4;
        float4 s = *(const float4*)(SinSl + n);
#pragma unroll
        for (int j = 1; j < NSLAB; ++j) {
            float4 t = *(const float4*)(SinSl + (size_t)j * KPAD + n);
            s.x += t.x; s.y += t.y; s.z += t.z; s.w += t.w;
        }
        float4 o;
        o.x = (n + 0 < KDIM) ? 1.0f / (1000.0f * s.x) : 0.0f;
        o.y = (n + 1 < KDIM) ? 1.0f / (1000.0f * s.y) : 0.0f;
        o.z = (n + 2 < KDIM) ? 1.0f / (1000.0f * s.z) : 0.0f;
        o.w = (n + 3 < KDIM) ? 1.0f / (1000.0f * s.w) : 0.0f;
        *(float4*)(rl + n) = o;
    }
    __syncthreads();
    int wave = tid >> 6, lane = tid & 63;
    int n0 = lane * 16;
    float rv[16];
#pragma unroll
    for (int i = 0; i < 16; ++i) rv[i] = rl[n0 + i];

    int x = bid & 7, ii = bid >> 3;
    int p = x + 8 * (ii % 12);            // panel [0,96), p%8 == x
    int st = ii / 12;                     // strip [0,8)
    int rowbase = p * 128 + st * 16 + wave * 4;
    const f16* erb = E16 + (size_t)rowbase * KPAD + n0;
    f16x8 e[4][2];
#pragma unroll
    for (int j = 0; j < 4; ++j) {
        e[j][0] = *(const f16x8*)(erb + (size_t)j * KPAD);
        e[j][1] = *(const f16x8*)(erb + (size_t)j * KPAD + 8);
    }
    float pr[4];
#pragma unroll
    for (int j = 0; j < 4; ++j) {
        float acc = 0.f;
#pragma unroll
        for (int i = 0; i < 8; ++i) {
            acc += (float)e[j][0][i] * rv[i];
            acc += (float)e[j][1][i] * rv[8 + i];
        }
        pr[j] = acc;
    }
#pragma unroll
    for (int m = 32; m >= 1; m >>= 1) {
        float t0 = __shfl_xor(pr[0], m, 64);
        float t1 = __shfl_xor(pr[1], m, 64);
        float t2 = __shfl_xor(pr[2], m, 64);
        float t3 = __shfl_xor(pr[3], m, 64);
        pr[0] += t0; pr[1] += t1; pr[2] += t2; pr[3] += t3;
    }
    float c[4];
#pragma unroll
    for (int j = 0; j < 4; ++j) c[j] = 1.0f / (12288.0f * pr[j]);
    float ca[16];
#pragma unroll
    for (int i = 0; i < 16; ++i) {
        int h = i >> 3, iv = i & 7;
        ca[i] = (float)e[0][h][iv] * c[0] + (float)e[1][h][iv] * c[1]
              + (float)e[2][h][iv] * c[2] + (float)e[3][h][iv] * c[3];
    }
#pragma unroll
    for (int i = 0; i < 16; ++i) {
        int idx = (i + lane) & 15;
        cols4[wave][n0 + idx] = ca[idx];
    }
    __syncthreads();
    float* outSlab = SoutSl + (size_t)x * KPAD;
    for (int n = tid; n < KPAD; n += 256)
        atomicAdd(&outSlab[n],
                  cols4[0][n] + cols4[1][n] + cols4[2][n] + cols4[3][n]);
}

// ---------------------------------------------------------------------------
// out: XCD-aligned remap over the 32 feats panels: (x, i%4, i/4) <-> (p, s),
// 8*4*32 = 1024 blocks, 4 rows each.
__global__ __launch_bounds__(256)
void out_k(const f16* __restrict__ E16, const float* __restrict__ S2sl,
           float* __restrict__ out) {
    __shared__ float rl[KPAD];
    int tid = threadIdx.x;
    {
        int n = tid * 4;
        float4 s = *(const float4*)(S2sl + n);
#pragma unroll
        for (int j = 1; j < NSLAB; ++j) {
            float4 t = *(const float4*)(S2sl + (size_t)j * KPAD + n);
            s.x += t.x; s.y += t.y; s.z += t.z; s.w += t.w;
        }
        float4 o;
        o.x = (n + 0 < KDIM) ? 1.0f / (1000.0f * s.x) : 0.0f;
        o.y = (n + 1 < KDIM) ? 1.0f / (1000.0f * s.y) : 0.0f;
        o.z = (n + 2 < KDIM) ? 1.0f / (1000.0f * s.z) : 0.0f;
        o.w = (n + 3 < KDIM) ? 1.0f / (1000.0f * s.w) : 0.0f;
        *(float4*)(rl + n) = o;
    }
    __syncthreads();
    int wave = tid >> 6, lane = tid & 63;
    int n0 = lane * 16;
    float rv[16];
#pragma unroll
    for (int i = 0; i < 16; ++i) rv[i] = rl[n0 + i];
    int bid = blockIdx.x;
    int x = bid & 7, ii = bid >> 3;
    int p = x + 8 * (ii % 4);             // panel [0,32), p%8 == x
    int st = ii / 4;                      // [0,32)
    int row = p * 128 + st * 4 + wave;
    const f16* er = E16 + (size_t)row * KPAD + n0;
    f16x8 e0 = *(const f16x8*)er;
    f16x8 e1 = *(const f16x8*)(er + 8);
    float w[16];
    float pv = 0.f;
#pragma unroll
    for (int i = 0; i < 8; ++i) {
        w[i] = (float)e0[i] * rv[i];
        w[8 + i] = (float)e1[i] * rv[8 + i];
    }
#pragma unroll
    for (int i = 0; i < 16; ++i) pv += w[i];
    pv = wsum(pv);
    float inv = 1.0f / pv;
    float* orow = out + (size_t)row * KDIM;
#pragma unroll
    for (int i = 0; i < 16; i += 4) {
        int n = n0 + i;
        if (n + 3 < KDIM) {   // KDIM%4==0: quad fully valid or fully out
            float4 o = { w[i] * inv, w[i + 1] * inv, w[i + 2] * inv, w[i + 3] * inv };
            *(float4*)(orow + n) = o;
        }
    }
}

// ---------------------------------------------------------------------------
extern "C" void kernel_launch(void* const* d_in, const int* in_sizes, int n_in,
                              void* d_out, int out_size, void* d_ws, size_t ws_size,
                              hipStream_t stream) {
    (void)in_sizes; (void)n_in; (void)out_size; (void)ws_size;
    const float* feats = (const float*)d_in[0];   // [4096,256]
    const float* head  = (const float*)d_in[1];   // [256,1000]
    const float* queue = (const float*)d_in[2];   // [8192,256]
    float* out = (float*)d_out;                   // [4096,1000]

    char* ws = (char*)d_ws;
    f16*   Bf    = (f16*)(ws + OFF_BF);
    f16*   E16   = (f16*)(ws + OFF_E16);
    float* slabs = (float*)(ws + OFF_SL);
    float* S0sl  = slabs;
    float* S1sl  = slabs + NSLAB * KPAD;
    float* S2sl  = slabs + 2 * NSLAB * KPAD;

    prep_k<<<56, 256, 0, stream>>>(head, Bf, slabs);
    gemm_exp_k<<<768, 256, 0, stream>>>(feats, queue, Bf, E16, S0sl);
    rowpass_k<<<768, 256, 0, stream>>>(E16, S0sl, S1sl);
    rowpass_k<<<768, 256, 0, stream>>>(E16, S1sl, S2sl);
    out_k<<<1024, 256, 0, stream>>>(E16, S2sl, out);
}